// Round 1
// baseline (375.534 us; speedup 1.0000x reference)
//
#include <hip/hip_runtime.h>

typedef unsigned short u16;
typedef __attribute__((ext_vector_type(8))) short bf16x8;
typedef __attribute__((ext_vector_type(4))) float f32x4;

__device__ __forceinline__ u16 f2bf(float x) {
  unsigned u = __float_as_uint(x);
  u = (u + 0x7FFFu + ((u >> 16) & 1u)) >> 16;
  return (u16)u;
}

// ---------- prep: l1/l2/l3 -> bf16 [512][288], append 1 at col 256, zero-pad ----------
__global__ void prep_l_kernel(const float* __restrict__ l1,
                              const float* __restrict__ l2,
                              const float* __restrict__ l3,
                              u16* __restrict__ o1, u16* __restrict__ o2,
                              u16* __restrict__ o3) {
  int idx = blockIdx.x * 256 + threadIdx.x;
  const int NR = 512 * 288;
  if (idx >= 3 * NR) return;
  int which = idx / NR, rem = idx - which * NR;
  int r = rem / 288, p = rem - r * 288;
  const float* s = which == 0 ? l1 : which == 1 ? l2 : l3;
  u16* d = which == 0 ? o1 : which == 1 ? o2 : o3;
  float v = (p < 256) ? s[r * 256 + p] : (p == 256 ? 1.0f : 0.0f);
  d[rem] = f2bf(v);
}

// ---------- prep: W[a][b][c] fp32 -> W2[cc][b][a] bf16, zero-padded to 288 ----------
// grid: (a-tiles=9, cc-tiles=tc/32, b=288); block 256
__global__ void prep_w_kernel(const float* __restrict__ W, u16* __restrict__ W2,
                              int c0) {
  __shared__ float tile[32][33];
  const int a0 = blockIdx.x * 32, cc0 = blockIdx.y * 32, b = blockIdx.z;
  const int t = threadIdx.x;
#pragma unroll
  for (int p = 0; p < 4; ++p) {
    int idx = t + p * 256;
    int cl = idx & 31, r = idx >> 5;  // r = a-local, cl = c-local
    int a = a0 + r, c = c0 + cc0 + cl;
    float v = 0.0f;
    if (a < 257 && b < 257 && c < 257) v = W[((long)a * 257 + b) * 257 + c];
    tile[r][cl] = v;
  }
  __syncthreads();
#pragma unroll
  for (int p = 0; p < 4; ++p) {
    int idx = t + p * 256;
    int al = idx & 31, ccl = idx >> 5;  // al = a-local, ccl = c-local
    W2[((long)(cc0 + ccl) * 288 + b) * 288 + (a0 + al)] = f2bf(tile[al][ccl]);
  }
}

// ---------- generic batched NT GEMM: C[z][M][N] (+)= A[z>>aSh][M][K] * B[z>>bSh][N][K]^T
// bf16 inputs, fp32 accumulate; C is bf16 or fp32. BM=BN=128, BK=32, 256 thr / 4 waves.
__global__ __launch_bounds__(256) void gemm_nt(
    const u16* __restrict__ A, const u16* __restrict__ B, void* __restrict__ C,
    int M, int N, int K, int lda, int ldb, int ldc,
    long aBS, int aSh, long bBS, int bSh, long cBS,
    int c_bf16, int c_accum) {
  __shared__ u16 As[128 * 48];
  __shared__ u16 Bs[128 * 48];
  const int t = threadIdx.x;
  const int m0 = blockIdx.y * 128, n0 = blockIdx.x * 128;
  const long zb = blockIdx.z;
  A += (zb >> aSh) * aBS;
  B += (zb >> bSh) * bBS;

  const int lane = t & 63;
  const int w = t >> 6;
  const int wr = (w >> 1) * 64, wc = (w & 1) * 64;
  const int r16 = lane & 15;
  const int kb = (lane >> 4) * 8;

  f32x4 acc[4][4];
  const f32x4 zero = {0.f, 0.f, 0.f, 0.f};
#pragma unroll
  for (int i = 0; i < 4; ++i)
#pragma unroll
    for (int j = 0; j < 4; ++j) acc[i][j] = zero;

  for (int k0 = 0; k0 < K; k0 += 32) {
#pragma unroll
    for (int p = 0; p < 2; ++p) {
      int q = t + p * 256;
      int row = q >> 2;
      int ko = (q & 3) * 8;
      uint4 va = *(const uint4*)(A + (long)(m0 + row) * lda + k0 + ko);
      *(uint4*)(&As[row * 48 + ko]) = va;
      uint4 vb;
      int brow = n0 + row;
      if (brow < N) {
        vb = *(const uint4*)(B + (long)brow * ldb + k0 + ko);
      } else {
        vb = make_uint4(0u, 0u, 0u, 0u);
      }
      *(uint4*)(&Bs[row * 48 + ko]) = vb;
    }
    __syncthreads();
    bf16x8 af[4], bfr[4];
#pragma unroll
    for (int mi = 0; mi < 4; ++mi)
      af[mi] = *(const bf16x8*)(&As[(wr + mi * 16 + r16) * 48 + kb]);
#pragma unroll
    for (int ni = 0; ni < 4; ++ni)
      bfr[ni] = *(const bf16x8*)(&Bs[(wc + ni * 16 + r16) * 48 + kb]);
#pragma unroll
    for (int mi = 0; mi < 4; ++mi)
#pragma unroll
      for (int ni = 0; ni < 4; ++ni)
        acc[mi][ni] = __builtin_amdgcn_mfma_f32_16x16x32_bf16(
            af[mi], bfr[ni], acc[mi][ni], 0, 0, 0);
    __syncthreads();
  }

  const int rr = (lane >> 4) * 4;
  if (c_bf16) {
    u16* Cb = (u16*)C + zb * cBS;
#pragma unroll
    for (int mi = 0; mi < 4; ++mi) {
      int gm = m0 + wr + mi * 16 + rr;
#pragma unroll
      for (int ni = 0; ni < 4; ++ni) {
        int gc = n0 + wc + ni * 16 + r16;
        if (gc < N) {
#pragma unroll
          for (int r = 0; r < 4; ++r)
            Cb[(long)(gm + r) * ldc + gc] = f2bf(acc[mi][ni][r]);
        }
      }
    }
  } else {
    float* Cf = (float*)C + zb * cBS;
#pragma unroll
    for (int mi = 0; mi < 4; ++mi) {
      int gm = m0 + wr + mi * 16 + rr;
#pragma unroll
      for (int ni = 0; ni < 4; ++ni) {
        int gc = n0 + wc + ni * 16 + r16;
        if (gc < N) {
#pragma unroll
          for (int r = 0; r < 4; ++r) {
            long idx = (long)(gm + r) * ldc + gc;
            float v = acc[mi][ni][r];
            if (c_accum) Cf[idx] += v; else Cf[idx] = v;
          }
        }
      }
    }
  }
}

extern "C" void kernel_launch(void* const* d_in, const int* in_sizes, int n_in,
                              void* d_out, int out_size, void* d_ws, size_t ws_size,
                              hipStream_t stream) {
  const float* l1 = (const float*)d_in[0];
  const float* l2 = (const float*)d_in[1];
  const float* l3 = (const float*)d_in[2];
  const float* W = (const float*)d_in[3];
  float* out = (float*)d_out;
  char* ws = (char*)d_ws;

  const long LB = 512L * 288 * 2;  // 294,912 B per l-buffer
  u16* l1b = (u16*)ws;
  u16* l2b = (u16*)(ws + LB);
  u16* l3b = (u16*)(ws + 2 * LB);
  char* pool = ws + 3 * LB;

  // Per unit of c: shared(W2|T2) = max(288*288*2, 512*256*2)=262144 ; T1 = 512*288*2 = 294912
  long avail = (long)ws_size - 3 * LB;
  int Tc = (int)(avail / 557056L);
  Tc &= ~31;
  if (Tc > 256) Tc = 256;
  if (Tc < 32) Tc = 32;  // smallest workable chunk

  u16* SH = (u16*)pool;                              // W2, later aliased as T2
  u16* T1 = (u16*)(pool + (long)Tc * 262144L);       // [512][Tc][288] bf16

  prep_l_kernel<<<1728, 256, 0, stream>>>(l1, l2, l3, l1b, l2b, l3b);

  int c0 = 0;
  while (c0 < 288) {
    int tc = (288 - c0 < Tc) ? (288 - c0) : Tc;

    // W2[cc][b][a] (bf16, zero-padded) for c in [c0, c0+tc)
    dim3 gw(9, tc / 32, 288);
    prep_w_kernel<<<gw, 256, 0, stream>>>(W, SH, c0);

    // stage 1: T1[512][(cc,b)] = l1b[512][288a] @ W2[(cc,b)][288a]^T
    dim3 g1(tc * 288 / 128, 4, 1);
    gemm_nt<<<g1, 256, 0, stream>>>(l1b, SH, T1,
        512, tc * 288, 288, 288, 288, tc * 288,
        0L, 0, 0L, 0, 0L, 1, 0);

    // stage 2: T2[ni][256j][tc cc] = l2b[n][256j][288b] @ T1[ni][cc][288b]^T
    dim3 g2((tc + 127) / 128, 2, 512);
    gemm_nt<<<g2, 256, 0, stream>>>(l2b, T1, SH,
        256, tc, 288, 288, 288, tc,
        256L * 288, 8, (long)tc * 288, 0, 256L * tc, 1, 0);

    // stage 3: out[ni][256j][256k] (+)= T2[ni][j][tc] @ l3b[n][k][tc at c0]^T
    dim3 g3(2, 2, 512);
    gemm_nt<<<g3, 256, 0, stream>>>(SH, l3b + c0, out,
        256, 256, tc, tc, 288, 256,
        256L * tc, 0, 256L * 288, 8, 65536L, 0, (c0 > 0) ? 1 : 0);

    c0 += tc;
  }
}

// Round 2
// 262.089 us; speedup vs baseline: 1.4328x; 1.4328x over previous
//
#include <hip/hip_runtime.h>

typedef unsigned short u16;
typedef __attribute__((ext_vector_type(8))) short bf16x8;
typedef __attribute__((ext_vector_type(4))) float f32x4;

__device__ __forceinline__ u16 f2bf(float x) {
  unsigned u = __float_as_uint(x);
  u = (u + 0x7FFFu + ((u >> 16) & 1u)) >> 16;
  return (u16)u;
}

// ---------- prep: l1/l2/l3 -> bf16 [512][288], append 1 at col 256, zero-pad ----------
__global__ void prep_l_kernel(const float* __restrict__ l1,
                              const float* __restrict__ l2,
                              const float* __restrict__ l3,
                              u16* __restrict__ o1, u16* __restrict__ o2,
                              u16* __restrict__ o3) {
  int idx = blockIdx.x * 256 + threadIdx.x;
  const int NR = 512 * 288;
  if (idx >= 3 * NR) return;
  int which = idx / NR, rem = idx - which * NR;
  int r = rem / 288, p = rem - r * 288;
  const float* s = which == 0 ? l1 : which == 1 ? l2 : l3;
  u16* d = which == 0 ? o1 : which == 1 ? o2 : o3;
  float v = (p < 256) ? s[r * 256 + p] : (p == 256 ? 1.0f : 0.0f);
  d[rem] = f2bf(v);
}

// ---------- prep: W[a][b][c] fp32 -> W2[c][b][a] bf16, zero-padded to 288 ----------
// grid: (a-tiles=9, c-tiles=9, b=288); block 256. Full c range in one shot.
__global__ void prep_w_kernel(const float* __restrict__ W, u16* __restrict__ W2) {
  __shared__ float tile[32][33];
  const int a0 = blockIdx.x * 32, c0 = blockIdx.y * 32, b = blockIdx.z;
  const int t = threadIdx.x;
#pragma unroll
  for (int p = 0; p < 4; ++p) {
    int idx = t + p * 256;
    int cl = idx & 31, r = idx >> 5;  // r = a-local, cl = c-local
    int a = a0 + r, c = c0 + cl;
    float v = 0.0f;
    if (a < 257 && b < 257 && c < 257) v = W[((long)a * 257 + b) * 257 + c];
    tile[r][cl] = v;
  }
  __syncthreads();
#pragma unroll
  for (int p = 0; p < 4; ++p) {
    int idx = t + p * 256;
    int al = idx & 31, ccl = idx >> 5;
    W2[((long)(c0 + ccl) * 288 + b) * 288 + (a0 + al)] = f2bf(tile[al][ccl]);
  }
}

// ---------- stage-1 NT GEMM: C[M][N] = A[M][K] * B[N][K]^T, bf16 in, bf16 out ----------
// BM=BN=128, BK=32, 256 thr / 4 waves. N multiple of 128 assumed here.
__global__ __launch_bounds__(256) void gemm_nt(
    const u16* __restrict__ A, const u16* __restrict__ B, u16* __restrict__ C,
    int K, int lda, int ldb, int ldc) {
  __shared__ u16 As[128 * 48];
  __shared__ u16 Bs[128 * 48];
  const int t = threadIdx.x;
  const int m0 = blockIdx.y * 128, n0 = blockIdx.x * 128;

  const int lane = t & 63;
  const int w = t >> 6;
  const int wr = (w >> 1) * 64, wc = (w & 1) * 64;
  const int r16 = lane & 15;
  const int kb = (lane >> 4) * 8;

  f32x4 acc[4][4];
  const f32x4 zero = {0.f, 0.f, 0.f, 0.f};
#pragma unroll
  for (int i = 0; i < 4; ++i)
#pragma unroll
    for (int j = 0; j < 4; ++j) acc[i][j] = zero;

  for (int k0 = 0; k0 < K; k0 += 32) {
#pragma unroll
    for (int p = 0; p < 2; ++p) {
      int q = t + p * 256;
      int row = q >> 2;
      int ko = (q & 3) * 8;
      uint4 va = *(const uint4*)(A + (long)(m0 + row) * lda + k0 + ko);
      *(uint4*)(&As[row * 48 + ko]) = va;
      uint4 vb = *(const uint4*)(B + (long)(n0 + row) * ldb + k0 + ko);
      *(uint4*)(&Bs[row * 48 + ko]) = vb;
    }
    __syncthreads();
    bf16x8 af[4], bfr[4];
#pragma unroll
    for (int mi = 0; mi < 4; ++mi)
      af[mi] = *(const bf16x8*)(&As[(wr + mi * 16 + r16) * 48 + kb]);
#pragma unroll
    for (int ni = 0; ni < 4; ++ni)
      bfr[ni] = *(const bf16x8*)(&Bs[(wc + ni * 16 + r16) * 48 + kb]);
#pragma unroll
    for (int mi = 0; mi < 4; ++mi)
#pragma unroll
      for (int ni = 0; ni < 4; ++ni)
        acc[mi][ni] = __builtin_amdgcn_mfma_f32_16x16x32_bf16(
            af[mi], bfr[ni], acc[mi][ni], 0, 0, 0);
    __syncthreads();
  }

  const int rr = (lane >> 4) * 4;
#pragma unroll
  for (int mi = 0; mi < 4; ++mi) {
    int gm = m0 + wr + mi * 16 + rr;
#pragma unroll
    for (int ni = 0; ni < 4; ++ni) {
      int gc = n0 + wc + ni * 16 + r16;
#pragma unroll
      for (int r = 0; r < 4; ++r)
        C[(long)(gm + r) * ldc + gc] = f2bf(acc[mi][ni][r]);
    }
  }
}

// ---------- fused stage 2+3: per (ni, j-tile of 64) ----------
// Phase A: S[64j][288c] (LDS, bf16) = l2[n][jt*64+j][b] . T1[ni][c][b]  (K=b=288)
// Phase B: out[ni][jt*64+j][k]      = S[j][c] . l3[n][k][c]             (K=c=288)
__global__ __launch_bounds__(256) void fused23(
    const u16* __restrict__ l2b, const u16* __restrict__ l3b,
    const u16* __restrict__ T1, float* __restrict__ out) {
  __shared__ u16 S[64 * 296];  // pad 288->296: 16-row frag reads hit all 32 banks
  const int t = threadIdx.x;
  const int lane = t & 63;
  const int w = t >> 6;
  const int jt = blockIdx.x;  // 0..3
  const int ni = blockIdx.y;  // 0..511
  const int n = ni >> 8;
  const int r16 = lane & 15;
  const int kb = (lane >> 4) * 8;
  const int rr = (lane >> 4) * 4;
  const f32x4 zero = {0.f, 0.f, 0.f, 0.f};

  // ---- phase A ----
  {
    const u16* A = l2b + (long)n * 256 * 288 + (long)jt * 64 * 288;
    const u16* Bq = T1 + (long)ni * 82944;  // [288 c][288 b]
    const int wr = (w >> 1) * 32;   // j-local: 0 / 32
    const int wc = (w & 1) * 144;   // c: 0 / 144
    f32x4 acc[2][9];
#pragma unroll
    for (int i = 0; i < 2; ++i)
#pragma unroll
      for (int j = 0; j < 9; ++j) acc[i][j] = zero;
    for (int k0 = 0; k0 < 288; k0 += 32) {
      bf16x8 af[2];
#pragma unroll
      for (int mi = 0; mi < 2; ++mi)
        af[mi] = *(const bf16x8*)(A + (long)(wr + mi * 16 + r16) * 288 + k0 + kb);
#pragma unroll
      for (int nj = 0; nj < 9; ++nj) {
        bf16x8 bf = *(const bf16x8*)(Bq + (long)(wc + nj * 16 + r16) * 288 + k0 + kb);
#pragma unroll
        for (int mi = 0; mi < 2; ++mi)
          acc[mi][nj] = __builtin_amdgcn_mfma_f32_16x16x32_bf16(
              af[mi], bf, acc[mi][nj], 0, 0, 0);
      }
    }
#pragma unroll
    for (int mi = 0; mi < 2; ++mi)
#pragma unroll
      for (int nj = 0; nj < 9; ++nj)
#pragma unroll
        for (int q = 0; q < 4; ++q)
          S[(wr + mi * 16 + rr + q) * 296 + wc + nj * 16 + r16] =
              f2bf(acc[mi][nj][q]);
  }
  __syncthreads();

  // ---- phase B ----
  {
    const u16* B3 = l3b + (long)n * 256 * 288;  // rows k, cols c
    const int vr = (w >> 1) * 32;   // j-local
    const int vc = (w & 1) * 128;   // k
    f32x4 acc[2][8];
#pragma unroll
    for (int i = 0; i < 2; ++i)
#pragma unroll
      for (int j = 0; j < 8; ++j) acc[i][j] = zero;
    for (int k0 = 0; k0 < 288; k0 += 32) {
      bf16x8 af[2];
#pragma unroll
      for (int mi = 0; mi < 2; ++mi)
        af[mi] = *(const bf16x8*)(&S[(vr + mi * 16 + r16) * 296 + k0 + kb]);
#pragma unroll
      for (int nj = 0; nj < 8; ++nj) {
        bf16x8 bf = *(const bf16x8*)(B3 + (long)(vc + nj * 16 + r16) * 288 + k0 + kb);
#pragma unroll
        for (int mi = 0; mi < 2; ++mi)
          acc[mi][nj] = __builtin_amdgcn_mfma_f32_16x16x32_bf16(
              af[mi], bf, acc[mi][nj], 0, 0, 0);
      }
    }
    float* O = out + (long)ni * 65536 + (long)jt * 64 * 256;
#pragma unroll
    for (int mi = 0; mi < 2; ++mi)
#pragma unroll
      for (int nj = 0; nj < 8; ++nj)
#pragma unroll
        for (int q = 0; q < 4; ++q)
          O[(long)(vr + mi * 16 + rr + q) * 256 + vc + nj * 16 + r16] =
              acc[mi][nj][q];
  }
}

extern "C" void kernel_launch(void* const* d_in, const int* in_sizes, int n_in,
                              void* d_out, int out_size, void* d_ws, size_t ws_size,
                              hipStream_t stream) {
  const float* l1 = (const float*)d_in[0];
  const float* l2 = (const float*)d_in[1];
  const float* l3 = (const float*)d_in[2];
  const float* W = (const float*)d_in[3];
  float* out = (float*)d_out;
  char* ws = (char*)d_ws;

  const long LB = 512L * 288 * 2;  // per l-buffer (294,912 B)
  u16* l1b = (u16*)ws;
  u16* l2b = (u16*)(ws + LB);
  u16* l3b = (u16*)(ws + 2 * LB);
  u16* T1 = (u16*)(ws + 3 * LB);  // [512][288c][288b] bf16 = 84.9 MB
  // W2 lives in d_out (134 MB): it is dead by the time fused23 overwrites out.
  u16* W2 = (u16*)d_out;  // [288c][288b][288a] bf16 = 47.8 MB

  prep_l_kernel<<<1728, 256, 0, stream>>>(l1, l2, l3, l1b, l2b, l3b);

  dim3 gw(9, 9, 288);
  prep_w_kernel<<<gw, 256, 0, stream>>>(W, W2);

  // stage 1: T1[512][(c,b)] = l1b[512][288a] @ W2[(c,b)][288a]^T
  dim3 g1(288 * 288 / 128, 4, 1);  // (648, 4)
  gemm_nt<<<g1, 256, 0, stream>>>(l1b, W2, T1, 288, 288, 288, 82944);

  // fused stage 2+3
  dim3 g2(4, 512, 1);
  fused23<<<g2, 256, 0, stream>>>(l2b, l3b, T1, out);
}

// Round 3
// 215.873 us; speedup vs baseline: 1.7396x; 1.2141x over previous
//
#include <hip/hip_runtime.h>

typedef unsigned short u16;
typedef __attribute__((ext_vector_type(8))) short bf16x8;
typedef __attribute__((ext_vector_type(4))) float f32x4;

__device__ __forceinline__ u16 f2bf(float x) {
  unsigned u = __float_as_uint(x);
  u = (u + 0x7FFFu + ((u >> 16) & 1u)) >> 16;
  return (u16)u;
}

// ---------- prep: l1/l2/l3 -> bf16 [512][288], append 1 at col 256, zero-pad ----------
__global__ void prep_l_kernel(const float* __restrict__ l1,
                              const float* __restrict__ l2,
                              const float* __restrict__ l3,
                              u16* __restrict__ o1, u16* __restrict__ o2,
                              u16* __restrict__ o3) {
  int idx = blockIdx.x * 256 + threadIdx.x;
  const int NR = 512 * 288;
  if (idx >= 3 * NR) return;
  int which = idx / NR, rem = idx - which * NR;
  int r = rem / 288, p = rem - r * 288;
  const float* s = which == 0 ? l1 : which == 1 ? l2 : l3;
  u16* d = which == 0 ? o1 : which == 1 ? o2 : o3;
  float v = (p < 256) ? s[r * 256 + p] : (p == 256 ? 1.0f : 0.0f);
  d[rem] = f2bf(v);
}

// ---------- prep: W[a][b][c] fp32 -> W2[c][b][a] bf16, zero-padded to 288 ----------
__global__ void prep_w_kernel(const float* __restrict__ W, u16* __restrict__ W2) {
  __shared__ float tile[32][33];
  const int a0 = blockIdx.x * 32, c0 = blockIdx.y * 32, b = blockIdx.z;
  const int t = threadIdx.x;
#pragma unroll
  for (int p = 0; p < 4; ++p) {
    int idx = t + p * 256;
    int cl = idx & 31, r = idx >> 5;
    int a = a0 + r, c = c0 + cl;
    float v = 0.0f;
    if (a < 257 && b < 257 && c < 257) v = W[((long)a * 257 + b) * 257 + c];
    tile[r][cl] = v;
  }
  __syncthreads();
#pragma unroll
  for (int p = 0; p < 4; ++p) {
    int idx = t + p * 256;
    int al = idx & 31, ccl = idx >> 5;
    W2[((long)(c0 + ccl) * 288 + b) * 288 + (a0 + al)] = f2bf(tile[al][ccl]);
  }
}

// ---------- stage-1 NT GEMM: C[M][N] = A[M][K] * B[N][K]^T, bf16 in/out ----------
__global__ __launch_bounds__(256) void gemm_nt(
    const u16* __restrict__ A, const u16* __restrict__ B, u16* __restrict__ C,
    int K, int lda, int ldb, int ldc) {
  __shared__ u16 As[128 * 48];
  __shared__ u16 Bs[128 * 48];
  const int t = threadIdx.x;
  const int m0 = blockIdx.y * 128, n0 = blockIdx.x * 128;
  const int lane = t & 63;
  const int w = t >> 6;
  const int wr = (w >> 1) * 64, wc = (w & 1) * 64;
  const int r16 = lane & 15;
  const int kb = (lane >> 4) * 8;

  f32x4 acc[4][4];
  const f32x4 zero = {0.f, 0.f, 0.f, 0.f};
#pragma unroll
  for (int i = 0; i < 4; ++i)
#pragma unroll
    for (int j = 0; j < 4; ++j) acc[i][j] = zero;

  for (int k0 = 0; k0 < K; k0 += 32) {
#pragma unroll
    for (int p = 0; p < 2; ++p) {
      int q = t + p * 256;
      int row = q >> 2;
      int ko = (q & 3) * 8;
      uint4 va = *(const uint4*)(A + (long)(m0 + row) * lda + k0 + ko);
      *(uint4*)(&As[row * 48 + ko]) = va;
      uint4 vb = *(const uint4*)(B + (long)(n0 + row) * ldb + k0 + ko);
      *(uint4*)(&Bs[row * 48 + ko]) = vb;
    }
    __syncthreads();
    bf16x8 af[4], bfr[4];
#pragma unroll
    for (int mi = 0; mi < 4; ++mi)
      af[mi] = *(const bf16x8*)(&As[(wr + mi * 16 + r16) * 48 + kb]);
#pragma unroll
    for (int ni = 0; ni < 4; ++ni)
      bfr[ni] = *(const bf16x8*)(&Bs[(wc + ni * 16 + r16) * 48 + kb]);
#pragma unroll
    for (int mi = 0; mi < 4; ++mi)
#pragma unroll
      for (int ni = 0; ni < 4; ++ni)
        acc[mi][ni] = __builtin_amdgcn_mfma_f32_16x16x32_bf16(
            af[mi], bfr[ni], acc[mi][ni], 0, 0, 0);
    __syncthreads();
  }

  const int rr = (lane >> 4) * 4;
#pragma unroll
  for (int mi = 0; mi < 4; ++mi) {
    int gm = m0 + wr + mi * 16 + rr;
#pragma unroll
    for (int ni = 0; ni < 4; ++ni) {
      int gc = n0 + wc + ni * 16 + r16;
#pragma unroll
      for (int r = 0; r < 4; ++r)
        C[(long)(gm + r) * ldc + gc] = f2bf(acc[mi][ni][r]);
    }
  }
}

// ---------- fused stage 2+3: one block per ni, 8 waves ----------
// Phase A: S[256j][288c] (LDS) = l2[n][j][b] . T1[ni][c][b]   (K=b=288)
// Phase B: out[ni][j][k]       = S[j][c]     . l3[n][k][c]    (K=c=288)
__global__ __launch_bounds__(512, 2) void fused23(
    const u16* __restrict__ l2b, const u16* __restrict__ l3b,
    const u16* __restrict__ T1, float* __restrict__ out) {
  __shared__ u16 S[256 * 296];  // stride 296: 16B-aligned rows, 2-way banks (free)
  const int t = threadIdx.x;
  const int lane = t & 63;
  const int w = t >> 6;      // 0..7
  const int wm = w & 3;      // j-quadrant (64 rows each)
  const int wn = w >> 2;     // 0/1
  const int ni = blockIdx.x; // 0..511
  const int n = ni >> 8;
  const int r16 = lane & 15;
  const int kb = (lane >> 4) * 8;
  const int rr = (lane >> 4) * 4;
  const f32x4 zero = {0.f, 0.f, 0.f, 0.f};

  // ---- phase A: wave tile 64j x 144c ----
  {
    const u16* A = l2b + (long)n * 73728 + (long)(wm * 64) * 288;
    const u16* Bq = T1 + (long)ni * 82944 + (long)(wn * 144) * 288;
    f32x4 acc[4][9];
#pragma unroll
    for (int i = 0; i < 4; ++i)
#pragma unroll
      for (int j = 0; j < 9; ++j) acc[i][j] = zero;
    for (int k0 = 0; k0 < 288; k0 += 32) {
      bf16x8 af[4];
#pragma unroll
      for (int mi = 0; mi < 4; ++mi)
        af[mi] = *(const bf16x8*)(A + (long)(mi * 16 + r16) * 288 + k0 + kb);
#pragma unroll
      for (int nj = 0; nj < 9; ++nj) {
        bf16x8 bf = *(const bf16x8*)(Bq + (long)(nj * 16 + r16) * 288 + k0 + kb);
#pragma unroll
        for (int mi = 0; mi < 4; ++mi)
          acc[mi][nj] = __builtin_amdgcn_mfma_f32_16x16x32_bf16(
              af[mi], bf, acc[mi][nj], 0, 0, 0);
      }
    }
#pragma unroll
    for (int mi = 0; mi < 4; ++mi)
#pragma unroll
      for (int nj = 0; nj < 9; ++nj)
#pragma unroll
        for (int q = 0; q < 4; ++q)
          S[(wm * 64 + mi * 16 + rr + q) * 296 + wn * 144 + nj * 16 + r16] =
              f2bf(acc[mi][nj][q]);
  }
  __syncthreads();

  // ---- phase B: wave tile 64j x 128k ----
  {
    const u16* B3 = l3b + (long)n * 73728 + (long)(wn * 128) * 288;
    f32x4 acc[4][8];
#pragma unroll
    for (int i = 0; i < 4; ++i)
#pragma unroll
      for (int j = 0; j < 8; ++j) acc[i][j] = zero;
    for (int k0 = 0; k0 < 288; k0 += 32) {
      bf16x8 af[4];
#pragma unroll
      for (int mi = 0; mi < 4; ++mi)
        af[mi] = *(const bf16x8*)(&S[(wm * 64 + mi * 16 + r16) * 296 + k0 + kb]);
#pragma unroll
      for (int nj = 0; nj < 8; ++nj) {
        bf16x8 bf = *(const bf16x8*)(B3 + (long)(nj * 16 + r16) * 288 + k0 + kb);
#pragma unroll
        for (int mi = 0; mi < 4; ++mi)
          acc[mi][nj] = __builtin_amdgcn_mfma_f32_16x16x32_bf16(
              af[mi], bf, acc[mi][nj], 0, 0, 0);
      }
    }
    float* O = out + (long)ni * 65536 + (long)(wm * 64) * 256 + wn * 128;
#pragma unroll
    for (int mi = 0; mi < 4; ++mi)
#pragma unroll
      for (int nj = 0; nj < 8; ++nj)
#pragma unroll
        for (int q = 0; q < 4; ++q)
          O[(long)(mi * 16 + rr + q) * 256 + nj * 16 + r16] = acc[mi][nj][q];
  }
}

extern "C" void kernel_launch(void* const* d_in, const int* in_sizes, int n_in,
                              void* d_out, int out_size, void* d_ws, size_t ws_size,
                              hipStream_t stream) {
  const float* l1 = (const float*)d_in[0];
  const float* l2 = (const float*)d_in[1];
  const float* l3 = (const float*)d_in[2];
  const float* W = (const float*)d_in[3];
  float* out = (float*)d_out;
  char* ws = (char*)d_ws;

  const long LB = 512L * 288 * 2;
  u16* l1b = (u16*)ws;
  u16* l2b = (u16*)(ws + LB);
  u16* l3b = (u16*)(ws + 2 * LB);
  u16* T1 = (u16*)(ws + 3 * LB);  // [512][288c][288b] bf16 = 84.9 MB
  u16* W2 = (u16*)d_out;          // staged in d_out; dead before fused23 writes

  prep_l_kernel<<<1728, 256, 0, stream>>>(l1, l2, l3, l1b, l2b, l3b);

  dim3 gw(9, 9, 288);
  prep_w_kernel<<<gw, 256, 0, stream>>>(W, W2);

  // stage 1: T1[512][(c,b)] = l1b[512][288a] @ W2[(c,b)][288a]^T
  dim3 g1(288 * 288 / 128, 4, 1);
  gemm_nt<<<g1, 256, 0, stream>>>(l1b, W2, T1, 288, 288, 288, 82944);

  // fused stage 2+3: one block per ni
  fused23<<<512, 512, 0, stream>>>(l2b, l3b, T1, out);
}

// Round 4
// 196.791 us; speedup vs baseline: 1.9083x; 1.0970x over previous
//
#include <hip/hip_runtime.h>

typedef unsigned short u16;
typedef __attribute__((ext_vector_type(8))) short bf16x8;
typedef __attribute__((ext_vector_type(4))) float f32x4;

#define GLOAD_LDS16(gsrc, ldst)                                               \
  __builtin_amdgcn_global_load_lds(                                           \
      (const __attribute__((address_space(1))) void*)(gsrc),                  \
      (__attribute__((address_space(3))) void*)(ldst), 16, 0, 0)

__device__ __forceinline__ u16 f2bf(float x) {
  unsigned u = __float_as_uint(x);
  u = (u + 0x7FFFu + ((u >> 16) & 1u)) >> 16;
  return (u16)u;
}

// ---------- prep: l1/l2/l3 -> bf16 [512][288], append 1 at col 256, zero-pad ----------
__global__ void prep_l_kernel(const float* __restrict__ l1,
                              const float* __restrict__ l2,
                              const float* __restrict__ l3,
                              u16* __restrict__ o1, u16* __restrict__ o2,
                              u16* __restrict__ o3) {
  int idx = blockIdx.x * 256 + threadIdx.x;
  const int NR = 512 * 288;
  if (idx >= 3 * NR) return;
  int which = idx / NR, rem = idx - which * NR;
  int r = rem / 288, p = rem - r * 288;
  const float* s = which == 0 ? l1 : which == 1 ? l2 : l3;
  u16* d = which == 0 ? o1 : which == 1 ? o2 : o3;
  float v = (p < 256) ? s[r * 256 + p] : (p == 256 ? 1.0f : 0.0f);
  d[rem] = f2bf(v);
}

// ---------- prep: W[a][b][c] fp32 -> W2[c][b][a] bf16, zero-padded to 288 ----------
__global__ void prep_w_kernel(const float* __restrict__ W, u16* __restrict__ W2) {
  __shared__ float tile[32][33];
  const int a0 = blockIdx.x * 32, c0 = blockIdx.y * 32, b = blockIdx.z;
  const int t = threadIdx.x;
#pragma unroll
  for (int p = 0; p < 4; ++p) {
    int idx = t + p * 256;
    int cl = idx & 31, r = idx >> 5;
    int a = a0 + r, c = c0 + cl;
    float v = 0.0f;
    if (a < 257 && b < 257 && c < 257) v = W[((long)a * 257 + b) * 257 + c];
    tile[r][cl] = v;
  }
  __syncthreads();
#pragma unroll
  for (int p = 0; p < 4; ++p) {
    int idx = t + p * 256;
    int al = idx & 31, ccl = idx >> 5;
    W2[((long)(c0 + ccl) * 288 + b) * 288 + (a0 + al)] = f2bf(tile[al][ccl]);
  }
}

// ---------- stage-1 NT GEMM: C[M][N] = A[M][K] * B[N][K]^T, bf16 in/out ----------
// m97-style: global_load_lds width-16 into unpadded [128][32] LDS tiles.
__global__ __launch_bounds__(256) void gemm_nt(
    const u16* __restrict__ A, const u16* __restrict__ B, u16* __restrict__ C,
    int K, int lda, int ldb, int ldc) {
  __shared__ u16 As[128 * 32];
  __shared__ u16 Bs[128 * 32];
  const int t = threadIdx.x;
  const int m0 = blockIdx.y * 128, n0 = blockIdx.x * 128;
  const int lane = t & 63;
  const int w = t >> 6;
  const int wr = (w >> 1) * 64, wc = (w & 1) * 64;
  const int r16 = lane & 15;
  const int kb = (lane >> 4) * 8;

  // staging geometry: chunk = 16B; row = chunk>>2, col-u16 = (chunk&3)*8
  const int c0r = t >> 2, c0c = (t & 3) * 8;
  const int c1r = (t + 256) >> 2, c1c = ((t + 256) & 3) * 8;

  f32x4 acc[4][4];
  const f32x4 zero = {0.f, 0.f, 0.f, 0.f};
#pragma unroll
  for (int i = 0; i < 4; ++i)
#pragma unroll
    for (int j = 0; j < 4; ++j) acc[i][j] = zero;

  for (int k0 = 0; k0 < K; k0 += 32) {
    GLOAD_LDS16(A + (long)(m0 + c0r) * lda + k0 + c0c, &As[t * 8]);
    GLOAD_LDS16(A + (long)(m0 + c1r) * lda + k0 + c1c, &As[(t + 256) * 8]);
    GLOAD_LDS16(B + (long)(n0 + c0r) * ldb + k0 + c0c, &Bs[t * 8]);
    GLOAD_LDS16(B + (long)(n0 + c1r) * ldb + k0 + c1c, &Bs[(t + 256) * 8]);
    __syncthreads();
    bf16x8 af[4], bfr[4];
#pragma unroll
    for (int mi = 0; mi < 4; ++mi)
      af[mi] = *(const bf16x8*)(&As[(wr + mi * 16 + r16) * 32 + kb]);
#pragma unroll
    for (int ni = 0; ni < 4; ++ni)
      bfr[ni] = *(const bf16x8*)(&Bs[(wc + ni * 16 + r16) * 32 + kb]);
#pragma unroll
    for (int mi = 0; mi < 4; ++mi)
#pragma unroll
      for (int ni = 0; ni < 4; ++ni)
        acc[mi][ni] = __builtin_amdgcn_mfma_f32_16x16x32_bf16(
            af[mi], bfr[ni], acc[mi][ni], 0, 0, 0);
    __syncthreads();
  }

  const int rr = (lane >> 4) * 4;
#pragma unroll
  for (int mi = 0; mi < 4; ++mi) {
    int gm = m0 + wr + mi * 16 + rr;
#pragma unroll
    for (int ni = 0; ni < 4; ++ni) {
      int gc = n0 + wc + ni * 16 + r16;
#pragma unroll
      for (int r = 0; r < 4; ++r)
        C[(long)(gm + r) * ldc + gc] = f2bf(acc[mi][ni][r]);
    }
  }
}

// ---------- fused stage 2+3: two blocks per ni (j-halves), 8 waves each ----------
// Phase A: S[128j][288c] (LDS) = l2[n][jh*128+j][b] . T1[ni][c][b]  (K=b=288)
// Phase B: out[ni][jh*128+j][k] = S[j][c] . l3[n][k][c]             (K=c=288)
__global__ __launch_bounds__(512, 4) void fused23(
    const u16* __restrict__ l2b, const u16* __restrict__ l3b,
    const u16* __restrict__ T1, float* __restrict__ out) {
  __shared__ u16 S[128 * 296];
  const int t = threadIdx.x;
  const int lane = t & 63;
  const int w = t >> 6;  // 0..7

  // XCD-paired mapping: both j-halves of one ni land on the same XCD.
  const int bid = blockIdx.x;          // 0..1023
  const int xcd = bid & 7;
  const int seq = bid >> 3;            // 0..127
  const int ni = xcd * 64 + (seq >> 1);
  const int half = seq & 1;
  const int n = ni >> 8;

  const int r16 = lane & 15;
  const int kb = (lane >> 4) * 8;
  const int rr = (lane >> 4) * 4;
  const f32x4 zero = {0.f, 0.f, 0.f, 0.f};

  // ---- phase A: 8 waves = 4 j-chunks(32) x 2 c-chunks(144) ----
  {
    const int wm = w & 3, wn = w >> 2;
    const u16* A = l2b + (long)n * 73728 + (long)(half * 128 + wm * 32) * 288;
    const u16* Bq = T1 + (long)ni * 82944 + (long)(wn * 144) * 288;
    f32x4 acc[2][9];
#pragma unroll
    for (int i = 0; i < 2; ++i)
#pragma unroll
      for (int j = 0; j < 9; ++j) acc[i][j] = zero;
    for (int k0 = 0; k0 < 288; k0 += 32) {
      bf16x8 af[2];
#pragma unroll
      for (int mi = 0; mi < 2; ++mi)
        af[mi] = *(const bf16x8*)(A + (long)(mi * 16 + r16) * 288 + k0 + kb);
#pragma unroll
      for (int nj = 0; nj < 9; ++nj) {
        bf16x8 bf = *(const bf16x8*)(Bq + (long)(nj * 16 + r16) * 288 + k0 + kb);
#pragma unroll
        for (int mi = 0; mi < 2; ++mi)
          acc[mi][nj] = __builtin_amdgcn_mfma_f32_16x16x32_bf16(
              af[mi], bf, acc[mi][nj], 0, 0, 0);
      }
    }
#pragma unroll
    for (int mi = 0; mi < 2; ++mi)
#pragma unroll
      for (int nj = 0; nj < 9; ++nj)
#pragma unroll
        for (int q = 0; q < 4; ++q)
          S[(wm * 32 + mi * 16 + rr + q) * 296 + wn * 144 + nj * 16 + r16] =
              f2bf(acc[mi][nj][q]);
  }
  __syncthreads();

  // ---- phase B: 8 waves = 2 j-chunks(64) x 4 k-chunks(64) ----
  {
    const int wm = w & 1, wn = w >> 1;
    const u16* B3 = l3b + (long)n * 73728 + (long)(wn * 64) * 288;
    f32x4 acc[4][4];
#pragma unroll
    for (int i = 0; i < 4; ++i)
#pragma unroll
      for (int j = 0; j < 4; ++j) acc[i][j] = zero;
    for (int k0 = 0; k0 < 288; k0 += 32) {
      bf16x8 af[4];
#pragma unroll
      for (int mi = 0; mi < 4; ++mi)
        af[mi] = *(const bf16x8*)(&S[(wm * 64 + mi * 16 + r16) * 296 + k0 + kb]);
#pragma unroll
      for (int nj = 0; nj < 4; ++nj) {
        bf16x8 bf = *(const bf16x8*)(B3 + (long)(nj * 16 + r16) * 288 + k0 + kb);
#pragma unroll
        for (int mi = 0; mi < 4; ++mi)
          acc[mi][nj] = __builtin_amdgcn_mfma_f32_16x16x32_bf16(
              af[mi], bf, acc[mi][nj], 0, 0, 0);
      }
    }
    float* O = out + (long)ni * 65536 + (long)(half * 128 + wm * 64) * 256 + wn * 64;
#pragma unroll
    for (int mi = 0; mi < 4; ++mi)
#pragma unroll
      for (int nj = 0; nj < 4; ++nj)
#pragma unroll
        for (int q = 0; q < 4; ++q)
          O[(long)(mi * 16 + rr + q) * 256 + nj * 16 + r16] = acc[mi][nj][q];
  }
}

extern "C" void kernel_launch(void* const* d_in, const int* in_sizes, int n_in,
                              void* d_out, int out_size, void* d_ws, size_t ws_size,
                              hipStream_t stream) {
  const float* l1 = (const float*)d_in[0];
  const float* l2 = (const float*)d_in[1];
  const float* l3 = (const float*)d_in[2];
  const float* W = (const float*)d_in[3];
  float* out = (float*)d_out;
  char* ws = (char*)d_ws;

  const long LB = 512L * 288 * 2;
  u16* l1b = (u16*)ws;
  u16* l2b = (u16*)(ws + LB);
  u16* l3b = (u16*)(ws + 2 * LB);
  u16* T1 = (u16*)(ws + 3 * LB);  // [512][288c][288b] bf16 = 84.9 MB
  u16* W2 = (u16*)d_out;          // staged in d_out; dead before fused23 writes

  prep_l_kernel<<<1728, 256, 0, stream>>>(l1, l2, l3, l1b, l2b, l3b);

  dim3 gw(9, 9, 288);
  prep_w_kernel<<<gw, 256, 0, stream>>>(W, W2);

  // stage 1: T1[512][(c,b)] = l1b[512][288a] @ W2[(c,b)][288a]^T
  dim3 g1(288 * 288 / 128, 4, 1);
  gemm_nt<<<g1, 256, 0, stream>>>(l1b, W2, T1, 288, 288, 288, 82944);

  // fused stage 2+3: two blocks per ni, XCD-paired
  fused23<<<1024, 512, 0, stream>>>(l2b, l3b, T1, out);
}

// Round 5
// 176.788 us; speedup vs baseline: 2.1242x; 1.1131x over previous
//
#include <hip/hip_runtime.h>

typedef unsigned short u16;
typedef __attribute__((ext_vector_type(8))) short bf16x8;
typedef __attribute__((ext_vector_type(4))) float f32x4;

#define GLOAD_LDS16(gsrc, ldst)                                               \
  __builtin_amdgcn_global_load_lds(                                           \
      (const __attribute__((address_space(1))) void*)(gsrc),                  \
      (__attribute__((address_space(3))) void*)(ldst), 16, 0, 0)

__device__ __forceinline__ u16 f2bf(float x) {
  unsigned u = __float_as_uint(x);
  u = (u + 0x7FFFu + ((u >> 16) & 1u)) >> 16;
  return (u16)u;
}

// ---------- prep: l1/l2/l3 -> bf16 [512][288], append 1 at col 256, zero-pad ----------
__global__ void prep_l_kernel(const float* __restrict__ l1,
                              const float* __restrict__ l2,
                              const float* __restrict__ l3,
                              u16* __restrict__ o1, u16* __restrict__ o2,
                              u16* __restrict__ o3) {
  int idx = blockIdx.x * 256 + threadIdx.x;
  const int NR = 512 * 288;
  if (idx >= 3 * NR) return;
  int which = idx / NR, rem = idx - which * NR;
  int r = rem / 288, p = rem - r * 288;
  const float* s = which == 0 ? l1 : which == 1 ? l2 : l3;
  u16* d = which == 0 ? o1 : which == 1 ? o2 : o3;
  float v = (p < 256) ? s[r * 256 + p] : (p == 256 ? 1.0f : 0.0f);
  d[rem] = f2bf(v);
}

// ---------- prep: W[a][b][c] fp32 -> W2[c][b][a] bf16, zero-padded to 288 ----------
__global__ void prep_w_kernel(const float* __restrict__ W, u16* __restrict__ W2) {
  __shared__ float tile[32][33];
  const int a0 = blockIdx.x * 32, c0 = blockIdx.y * 32, b = blockIdx.z;
  const int t = threadIdx.x;
#pragma unroll
  for (int p = 0; p < 4; ++p) {
    int idx = t + p * 256;
    int cl = idx & 31, r = idx >> 5;
    int a = a0 + r, c = c0 + cl;
    float v = 0.0f;
    if (a < 257 && b < 257 && c < 257) v = W[((long)a * 257 + b) * 257 + c];
    tile[r][cl] = v;
  }
  __syncthreads();
#pragma unroll
  for (int p = 0; p < 4; ++p) {
    int idx = t + p * 256;
    int al = idx & 31, ccl = idx >> 5;
    W2[((long)(c0 + ccl) * 288 + b) * 288 + (a0 + al)] = f2bf(tile[al][ccl]);
  }
}

// ---------- stage-1 NT GEMM: C[M][N] = A[M][K] * B[N][K]^T, bf16 in/out ----------
__global__ __launch_bounds__(256) void gemm_nt(
    const u16* __restrict__ A, const u16* __restrict__ B, u16* __restrict__ C,
    int K, int lda, int ldb, int ldc) {
  __shared__ u16 As[128 * 32];
  __shared__ u16 Bs[128 * 32];
  const int t = threadIdx.x;
  const int m0 = blockIdx.y * 128, n0 = blockIdx.x * 128;
  const int lane = t & 63;
  const int w = t >> 6;
  const int wr = (w >> 1) * 64, wc = (w & 1) * 64;
  const int r16 = lane & 15;
  const int kb = (lane >> 4) * 8;
  const int c0r = t >> 2, c0c = (t & 3) * 8;
  const int c1r = (t + 256) >> 2, c1c = ((t + 256) & 3) * 8;

  f32x4 acc[4][4];
  const f32x4 zero = {0.f, 0.f, 0.f, 0.f};
#pragma unroll
  for (int i = 0; i < 4; ++i)
#pragma unroll
    for (int j = 0; j < 4; ++j) acc[i][j] = zero;

  for (int k0 = 0; k0 < K; k0 += 32) {
    GLOAD_LDS16(A + (long)(m0 + c0r) * lda + k0 + c0c, &As[t * 8]);
    GLOAD_LDS16(A + (long)(m0 + c1r) * lda + k0 + c1c, &As[(t + 256) * 8]);
    GLOAD_LDS16(B + (long)(n0 + c0r) * ldb + k0 + c0c, &Bs[t * 8]);
    GLOAD_LDS16(B + (long)(n0 + c1r) * ldb + k0 + c1c, &Bs[(t + 256) * 8]);
    __syncthreads();
    bf16x8 af[4], bfr[4];
#pragma unroll
    for (int mi = 0; mi < 4; ++mi)
      af[mi] = *(const bf16x8*)(&As[(wr + mi * 16 + r16) * 32 + kb]);
#pragma unroll
    for (int ni = 0; ni < 4; ++ni)
      bfr[ni] = *(const bf16x8*)(&Bs[(wc + ni * 16 + r16) * 32 + kb]);
#pragma unroll
    for (int mi = 0; mi < 4; ++mi)
#pragma unroll
      for (int ni = 0; ni < 4; ++ni)
        acc[mi][ni] = __builtin_amdgcn_mfma_f32_16x16x32_bf16(
            af[mi], bfr[ni], acc[mi][ni], 0, 0, 0);
    __syncthreads();
  }

  const int rr = (lane >> 4) * 4;
#pragma unroll
  for (int mi = 0; mi < 4; ++mi) {
    int gm = m0 + wr + mi * 16 + rr;
#pragma unroll
    for (int ni = 0; ni < 4; ++ni) {
      int gc = n0 + wc + ni * 16 + r16;
#pragma unroll
      for (int r = 0; r < 4; ++r)
        C[(long)(gm + r) * ldc + gc] = f2bf(acc[mi][ni][r]);
    }
  }
}

// ---------- fused stage 2+3: two blocks per ni (j-halves), 8 waves, LDS-staged dbuf ----------
// Phase A: S[128j][288c] (LDS) = l2[n][jh*128+j][b] . T1[ni][c][b]  (K=b=288)
// Phase B: out[ni][jh*128+j][k] = S[j][c] . l3[n][k][c]             (K=c=288)
__global__ __launch_bounds__(512, 2) void fused23(
    const u16* __restrict__ l2b, const u16* __restrict__ l3b,
    const u16* __restrict__ T1, float* __restrict__ out) {
  __shared__ u16 S[128 * 296];       // 75,776 B
  __shared__ u16 Ast[2][128 * 32];   // 16,384 B  (l2 k-slices)
  __shared__ u16 Bst[2][288 * 32];   // 36,864 B  (T1 / l3 k-slices)
  const int t = threadIdx.x;
  const int lane = t & 63;
  const int w = t >> 6;  // 0..7

  // XCD-paired mapping: both j-halves of one ni land on the same XCD.
  const int bid = blockIdx.x;  // 0..1023
  const int xcd = bid & 7;
  const int seq = bid >> 3;
  const int ni = xcd * 64 + (seq >> 1);
  const int half = seq & 1;
  const int n = ni >> 8;

  const int r16 = lane & 15;
  const int kb = (lane >> 4) * 8;
  const int rr = (lane >> 4) * 4;
  const f32x4 zero = {0.f, 0.f, 0.f, 0.f};

  const u16* A2 = l2b + (long)n * 73728 + (long)(half * 128) * 288;  // [128][288]
  const u16* BT = T1 + (long)ni * 82944;                             // [288][288]
  const u16* B3 = l3b + (long)n * 73728;                             // [256][288]

#define STAGE_A(buf, k0)                                                      \
  {                                                                           \
    int _r = t >> 2, _c = (t & 3) * 8;                                        \
    GLOAD_LDS16(A2 + (long)_r * 288 + (k0) + _c, &Ast[buf][t * 8]);           \
    _Pragma("unroll") for (int _p = 0; _p < 3; ++_p) {                        \
      int _q = t + _p * 512;                                                  \
      if (_q < 1152) {                                                        \
        int _br = _q >> 2, _bc = (_q & 3) * 8;                                \
        GLOAD_LDS16(BT + (long)_br * 288 + (k0) + _bc, &Bst[buf][_q * 8]);    \
      }                                                                       \
    }                                                                         \
  }

#define STAGE_B(buf, k0)                                                      \
  {                                                                           \
    _Pragma("unroll") for (int _p = 0; _p < 2; ++_p) {                        \
      int _q = t + _p * 512;                                                  \
      int _br = _q >> 2, _bc = (_q & 3) * 8;                                  \
      GLOAD_LDS16(B3 + (long)_br * 288 + (k0) + _bc, &Bst[buf][_q * 8]);      \
    }                                                                         \
  }

  // ---- phase A: 8 waves = 4 j-chunks(32) x 2 c-chunks(144) ----
  {
    const int wm = w & 3, wn = w >> 2;
    f32x4 acc[2][9];
#pragma unroll
    for (int i = 0; i < 2; ++i)
#pragma unroll
      for (int j = 0; j < 9; ++j) acc[i][j] = zero;

    STAGE_A(0, 0);
    __syncthreads();
    for (int ks = 0; ks < 9; ++ks) {
      const int cur = ks & 1;
      if (ks + 1 < 9) STAGE_A(cur ^ 1, (ks + 1) * 32);
      bf16x8 af[2], bf[9];
#pragma unroll
      for (int mi = 0; mi < 2; ++mi)
        af[mi] = *(const bf16x8*)(&Ast[cur][(wm * 32 + mi * 16 + r16) * 32 + kb]);
#pragma unroll
      for (int nj = 0; nj < 9; ++nj)
        bf[nj] = *(const bf16x8*)(&Bst[cur][(wn * 144 + nj * 16 + r16) * 32 + kb]);
#pragma unroll
      for (int nj = 0; nj < 9; ++nj)
#pragma unroll
        for (int mi = 0; mi < 2; ++mi)
          acc[mi][nj] = __builtin_amdgcn_mfma_f32_16x16x32_bf16(
              af[mi], bf[nj], acc[mi][nj], 0, 0, 0);
      __syncthreads();
    }
#pragma unroll
    for (int mi = 0; mi < 2; ++mi)
#pragma unroll
      for (int nj = 0; nj < 9; ++nj)
#pragma unroll
        for (int q = 0; q < 4; ++q)
          S[(wm * 32 + mi * 16 + rr + q) * 296 + wn * 144 + nj * 16 + r16] =
              f2bf(acc[mi][nj][q]);
  }
  // phase-B first slice DMA overlaps the S epilogue/barrier
  STAGE_B(0, 0);
  __syncthreads();

  // ---- phase B: 8 waves = 2 j-chunks(64) x 4 k-chunks(64) ----
  {
    const int wm = w & 1, wn = w >> 1;
    f32x4 acc[4][4];
#pragma unroll
    for (int i = 0; i < 4; ++i)
#pragma unroll
      for (int j = 0; j < 4; ++j) acc[i][j] = zero;

    for (int ks = 0; ks < 9; ++ks) {
      const int cur = ks & 1;
      if (ks + 1 < 9) STAGE_B(cur ^ 1, (ks + 1) * 32);
      bf16x8 af[4], bf[4];
#pragma unroll
      for (int mi = 0; mi < 4; ++mi)
        af[mi] = *(const bf16x8*)(&S[(wm * 64 + mi * 16 + r16) * 296 + ks * 32 + kb]);
#pragma unroll
      for (int nj = 0; nj < 4; ++nj)
        bf[nj] = *(const bf16x8*)(&Bst[cur][(wn * 64 + nj * 16 + r16) * 32 + kb]);
#pragma unroll
      for (int nj = 0; nj < 4; ++nj)
#pragma unroll
        for (int mi = 0; mi < 4; ++mi)
          acc[mi][nj] = __builtin_amdgcn_mfma_f32_16x16x32_bf16(
              af[mi], bf[nj], acc[mi][nj], 0, 0, 0);
      __syncthreads();
    }
    float* O = out + (long)ni * 65536 + (long)(half * 128 + wm * 64) * 256 + wn * 64;
#pragma unroll
    for (int mi = 0; mi < 4; ++mi)
#pragma unroll
      for (int nj = 0; nj < 4; ++nj)
#pragma unroll
        for (int q = 0; q < 4; ++q)
          O[(long)(mi * 16 + rr + q) * 256 + nj * 16 + r16] = acc[mi][nj][q];
  }
#undef STAGE_A
#undef STAGE_B
}

extern "C" void kernel_launch(void* const* d_in, const int* in_sizes, int n_in,
                              void* d_out, int out_size, void* d_ws, size_t ws_size,
                              hipStream_t stream) {
  const float* l1 = (const float*)d_in[0];
  const float* l2 = (const float*)d_in[1];
  const float* l3 = (const float*)d_in[2];
  const float* W = (const float*)d_in[3];
  float* out = (float*)d_out;
  char* ws = (char*)d_ws;

  const long LB = 512L * 288 * 2;
  u16* l1b = (u16*)ws;
  u16* l2b = (u16*)(ws + LB);
  u16* l3b = (u16*)(ws + 2 * LB);
  u16* T1 = (u16*)(ws + 3 * LB);  // [512][288c][288b] bf16 = 84.9 MB
  u16* W2 = (u16*)d_out;          // staged in d_out; dead before fused23 writes

  prep_l_kernel<<<1728, 256, 0, stream>>>(l1, l2, l3, l1b, l2b, l3b);

  dim3 gw(9, 9, 288);
  prep_w_kernel<<<gw, 256, 0, stream>>>(W, W2);

  // stage 1: T1[512][(c,b)] = l1b[512][288a] @ W2[(c,b)][288a]^T
  dim3 g1(288 * 288 / 128, 4, 1);
  gemm_nt<<<g1, 256, 0, stream>>>(l1b, W2, T1, 288, 288, 288, 82944);

  // fused stage 2+3: two blocks per ni, XCD-paired
  fused23<<<1024, 512, 0, stream>>>(l2b, l3b, T1, out);
}

// Round 6
// 163.978 us; speedup vs baseline: 2.2901x; 1.0781x over previous
//
#include <hip/hip_runtime.h>

typedef unsigned short u16;
typedef __attribute__((ext_vector_type(8))) short bf16x8;
typedef __attribute__((ext_vector_type(4))) float f32x4;

#define GLOAD_LDS16(gsrc, ldst)                                               \
  __builtin_amdgcn_global_load_lds(                                           \
      (const __attribute__((address_space(1))) void*)(gsrc),                  \
      (__attribute__((address_space(3))) void*)(ldst), 16, 0, 0)

__device__ __forceinline__ u16 f2bf(float x) {
  unsigned u = __float_as_uint(x);
  u = (u + 0x7FFFu + ((u >> 16) & 1u)) >> 16;
  return (u16)u;
}

// ---------- prep: l1/l2/l3 -> bf16 [512][288], append 1 at col 256, zero-pad ----------
__global__ void prep_l_kernel(const float* __restrict__ l1,
                              const float* __restrict__ l2,
                              const float* __restrict__ l3,
                              u16* __restrict__ o1, u16* __restrict__ o2,
                              u16* __restrict__ o3) {
  int idx = blockIdx.x * 256 + threadIdx.x;
  const int NR = 512 * 288;
  if (idx >= 3 * NR) return;
  int which = idx / NR, rem = idx - which * NR;
  int r = rem / 288, p = rem - r * 288;
  const float* s = which == 0 ? l1 : which == 1 ? l2 : l3;
  u16* d = which == 0 ? o1 : which == 1 ? o2 : o3;
  float v = (p < 256) ? s[r * 256 + p] : (p == 256 ? 1.0f : 0.0f);
  d[rem] = f2bf(v);
}

// ---------- prep: W[a][b][c] fp32 -> W2[c][b][a] bf16, zero-padded to 288 ----------
__global__ void prep_w_kernel(const float* __restrict__ W, u16* __restrict__ W2) {
  __shared__ float tile[32][33];
  const int a0 = blockIdx.x * 32, c0 = blockIdx.y * 32, b = blockIdx.z;
  const int t = threadIdx.x;
#pragma unroll
  for (int p = 0; p < 4; ++p) {
    int idx = t + p * 256;
    int cl = idx & 31, r = idx >> 5;
    int a = a0 + r, c = c0 + cl;
    float v = 0.0f;
    if (a < 257 && b < 257 && c < 257) v = W[((long)a * 257 + b) * 257 + c];
    tile[r][cl] = v;
  }
  __syncthreads();
#pragma unroll
  for (int p = 0; p < 4; ++p) {
    int idx = t + p * 256;
    int al = idx & 31, ccl = idx >> 5;
    W2[((long)(c0 + ccl) * 288 + b) * 288 + (a0 + al)] = f2bf(tile[al][ccl]);
  }
}

// ---------- stage-1 NT GEMM, XCD-grouped n-tile-major grid ----------
// C[M=512][N=82944] = A[512][288] * B[82944][288]^T. Grid 2592 flat:
// xcd = bid&7 owns n-tiles [xcd*81, xcd*81+81); the 4 m-blocks of one
// n-tile are consecutive -> B-tile fetched once into that XCD's L2.
__global__ __launch_bounds__(256) void gemm_nt(
    const u16* __restrict__ A, const u16* __restrict__ B, u16* __restrict__ C,
    int K, int lda, int ldb, int ldc) {
  __shared__ u16 As[128 * 32];
  __shared__ u16 Bs[128 * 32];
  const int t = threadIdx.x;
  const int bid = blockIdx.x;
  const int xcd = bid & 7, s = bid >> 3;
  const int nt = xcd * 81 + (s >> 2);
  const int mt = s & 3;
  const int m0 = mt * 128, n0 = nt * 128;
  const int lane = t & 63;
  const int w = t >> 6;
  const int wr = (w >> 1) * 64, wc = (w & 1) * 64;
  const int r16 = lane & 15;
  const int kb = (lane >> 4) * 8;
  const int c0r = t >> 2, c0c = (t & 3) * 8;
  const int c1r = (t + 256) >> 2, c1c = ((t + 256) & 3) * 8;

  f32x4 acc[4][4];
  const f32x4 zero = {0.f, 0.f, 0.f, 0.f};
#pragma unroll
  for (int i = 0; i < 4; ++i)
#pragma unroll
    for (int j = 0; j < 4; ++j) acc[i][j] = zero;

  for (int k0 = 0; k0 < K; k0 += 32) {
    GLOAD_LDS16(A + (long)(m0 + c0r) * lda + k0 + c0c, &As[t * 8]);
    GLOAD_LDS16(A + (long)(m0 + c1r) * lda + k0 + c1c, &As[(t + 256) * 8]);
    GLOAD_LDS16(B + (long)(n0 + c0r) * ldb + k0 + c0c, &Bs[t * 8]);
    GLOAD_LDS16(B + (long)(n0 + c1r) * ldb + k0 + c1c, &Bs[(t + 256) * 8]);
    __syncthreads();
    bf16x8 af[4], bfr[4];
#pragma unroll
    for (int mi = 0; mi < 4; ++mi)
      af[mi] = *(const bf16x8*)(&As[(wr + mi * 16 + r16) * 32 + kb]);
#pragma unroll
    for (int ni = 0; ni < 4; ++ni)
      bfr[ni] = *(const bf16x8*)(&Bs[(wc + ni * 16 + r16) * 32 + kb]);
#pragma unroll
    for (int mi = 0; mi < 4; ++mi)
#pragma unroll
      for (int ni = 0; ni < 4; ++ni)
        acc[mi][ni] = __builtin_amdgcn_mfma_f32_16x16x32_bf16(
            af[mi], bfr[ni], acc[mi][ni], 0, 0, 0);
    __syncthreads();
  }

  const int rr = (lane >> 4) * 4;
#pragma unroll
  for (int mi = 0; mi < 4; ++mi) {
    int gm = m0 + wr + mi * 16 + rr;
#pragma unroll
    for (int ni = 0; ni < 4; ++ni) {
      int gc = n0 + wc + ni * 16 + r16;
#pragma unroll
      for (int r = 0; r < 4; ++r)
        C[(long)(gm + r) * ldc + gc] = f2bf(acc[mi][ni][r]);
    }
  }
}

// ---------- fused stage 2+3: BK=64, swizzled staged B-operand, reg-staged l2 ----------
// Phase A: S[128j][288c] (LDS) = l2[n][jh*128+j][b] . T1[ni][c][b]  (K=b=288)
// Phase B: out[ni][jh*128+j][k] = S[j][c] . l3[n][k][c]             (K=c=288)
// Bst layout: row stride 64 u16 (128 B); 16B chunk at logical (r,c) stored at
// chunk index r*8 + (c ^ (r&7))  [T2 both-sides swizzle, rule #21].
__global__ __launch_bounds__(512, 2) void fused23(
    const u16* __restrict__ l2b, const u16* __restrict__ l3b,
    const u16* __restrict__ T1, float* __restrict__ out) {
  __shared__ u16 S[128 * 296];      // 75,776 B
  __shared__ u16 Bst[2][288 * 64];  // 73,728 B
  const int t = threadIdx.x;
  const int lane = t & 63;
  const int w = t >> 6;  // 0..7

  // XCD-paired mapping: both j-halves of one ni land on the same XCD.
  const int bid = blockIdx.x;  // 0..1023
  const int xcd = bid & 7;
  const int seq = bid >> 3;
  const int ni = xcd * 64 + (seq >> 1);
  const int half = seq & 1;
  const int n = ni >> 8;

  const int r16 = lane & 15;
  const int cgrp = lane >> 4;      // 0..3
  const int kb = cgrp * 8;
  const int rr = cgrp * 4;
  const f32x4 zero = {0.f, 0.f, 0.f, 0.f};

  const u16* A2 = l2b + (long)n * 73728 + (long)(half * 128) * 288;  // [128][288]
  const u16* BT = T1 + (long)ni * 82944;                             // [288][288]
  const u16* B3 = l3b + (long)n * 73728;                             // [256][288]

  // full 64-col slice: NCH = rows*8 chunks; source col pre-swizzled
#define STG_FULL(src, buf, k0, NCH)                                           \
  {                                                                           \
    _Pragma("unroll") for (int _p = 0; _p < 5; ++_p) {                        \
      int _q = t + _p * 512;                                                  \
      if (_q < (NCH)) {                                                       \
        int _r = _q >> 3, _c = (_q & 7) ^ (_r & 7);                           \
        GLOAD_LDS16(src + (long)_r * 288 + (k0) + _c * 8, &Bst[buf][_q * 8]); \
      }                                                                       \
    }                                                                         \
  }
  // tail 32-col slice: only logical cols 0..3 staged (others never read)
#define STG_TAIL(src, buf, k0, NCH)                                           \
  {                                                                           \
    _Pragma("unroll") for (int _p = 0; _p < 5; ++_p) {                        \
      int _q = t + _p * 512;                                                  \
      if (_q < (NCH)) {                                                       \
        int _r = _q >> 3, _c = (_q & 7) ^ (_r & 7);                           \
        if (_c < 4)                                                           \
          GLOAD_LDS16(src + (long)_r * 288 + (k0) + _c * 8, &Bst[buf][_q * 8]);\
      }                                                                       \
    }                                                                         \
  }
  // swizzled read: 16B chunk (R, c) at u16 offset R*64 + ((c^(R&7))*8)
#define BREAD(buf, R, c) \
  (*(const bf16x8*)(&Bst[buf][(R) * 64 + ((((c)) ^ ((R) & 7)) * 8)]))

  // ================= phase A =================
  {
    const int wm = w & 3, wn = w >> 2;
    const u16* a0p = A2 + (long)(wm * 32 + r16) * 288;
    const u16* a1p = a0p + 16 * 288;
    f32x4 acc[2][9];
#pragma unroll
    for (int i = 0; i < 2; ++i)
#pragma unroll
      for (int j = 0; j < 9; ++j) acc[i][j] = zero;

    STG_FULL(BT, 0, 0, 2304);
    bf16x8 afn[2][2];
    afn[0][0] = *(const bf16x8*)(a0p + kb);
    afn[0][1] = *(const bf16x8*)(a0p + 32 + kb);
    afn[1][0] = *(const bf16x8*)(a1p + kb);
    afn[1][1] = *(const bf16x8*)(a1p + 32 + kb);
    __syncthreads();

#pragma unroll
    for (int ks = 0; ks < 4; ++ks) {
      const int cur = ks & 1;
      if (ks < 3) STG_FULL(BT, cur ^ 1, (ks + 1) * 64, 2304)
      else        STG_TAIL(BT, cur ^ 1, 256, 2304)
      bf16x8 afc[2][2];
#pragma unroll
      for (int mi = 0; mi < 2; ++mi)
#pragma unroll
        for (int kk = 0; kk < 2; ++kk) afc[mi][kk] = afn[mi][kk];
      if (ks < 3) {
        const int nk = (ks + 1) * 64;
        afn[0][0] = *(const bf16x8*)(a0p + nk + kb);
        afn[0][1] = *(const bf16x8*)(a0p + nk + 32 + kb);
        afn[1][0] = *(const bf16x8*)(a1p + nk + kb);
        afn[1][1] = *(const bf16x8*)(a1p + nk + 32 + kb);
      } else {
        afn[0][0] = *(const bf16x8*)(a0p + 256 + kb);
        afn[1][0] = *(const bf16x8*)(a1p + 256 + kb);
      }
      bf16x8 bf[9][2];
#pragma unroll
      for (int nj = 0; nj < 9; ++nj) {
        const int R = wn * 144 + nj * 16 + r16;
        bf[nj][0] = BREAD(cur, R, cgrp);
        bf[nj][1] = BREAD(cur, R, 4 + cgrp);
      }
#pragma unroll
      for (int nj = 0; nj < 9; ++nj)
#pragma unroll
        for (int kk = 0; kk < 2; ++kk)
#pragma unroll
          for (int mi = 0; mi < 2; ++mi)
            acc[mi][nj] = __builtin_amdgcn_mfma_f32_16x16x32_bf16(
                afc[mi][kk], bf[nj][kk], acc[mi][nj], 0, 0, 0);
      __syncthreads();
    }
    // tail step ks=4 (cols 256..287), buffer 0, kk=0 only
#pragma unroll
    for (int nj = 0; nj < 9; ++nj) {
      const int R = wn * 144 + nj * 16 + r16;
      bf16x8 bf = BREAD(0, R, cgrp);
#pragma unroll
      for (int mi = 0; mi < 2; ++mi)
        acc[mi][nj] = __builtin_amdgcn_mfma_f32_16x16x32_bf16(
            afn[mi][0], bf, acc[mi][nj], 0, 0, 0);
    }
    __syncthreads();  // all tail reads of Bst[0] complete
    STG_FULL(B3, 0, 0, 2048);  // phase-B slice 0 DMA overlaps S epilogue
#pragma unroll
    for (int mi = 0; mi < 2; ++mi)
#pragma unroll
      for (int nj = 0; nj < 9; ++nj)
#pragma unroll
        for (int q = 0; q < 4; ++q)
          S[(wm * 32 + mi * 16 + rr + q) * 296 + wn * 144 + nj * 16 + r16] =
              f2bf(acc[mi][nj][q]);
  }
  __syncthreads();  // S visible + Bst[0] ready

  // ================= phase B =================
  {
    const int wm = w & 1, wn = w >> 1;
    f32x4 acc[4][4];
#pragma unroll
    for (int i = 0; i < 4; ++i)
#pragma unroll
      for (int j = 0; j < 4; ++j) acc[i][j] = zero;

#pragma unroll
    for (int ks = 0; ks < 4; ++ks) {
      const int cur = ks & 1;
      if (ks < 3) STG_FULL(B3, cur ^ 1, (ks + 1) * 64, 2048)
      else        STG_TAIL(B3, cur ^ 1, 256, 2048)
      bf16x8 af[4][2], bf[4][2];
#pragma unroll
      for (int mi = 0; mi < 4; ++mi) {
        af[mi][0] = *(const bf16x8*)(&S[(wm * 64 + mi * 16 + r16) * 296 + ks * 64 + kb]);
        af[mi][1] = *(const bf16x8*)(&S[(wm * 64 + mi * 16 + r16) * 296 + ks * 64 + 32 + kb]);
      }
#pragma unroll
      for (int nj = 0; nj < 4; ++nj) {
        const int R = wn * 64 + nj * 16 + r16;
        bf[nj][0] = BREAD(cur, R, cgrp);
        bf[nj][1] = BREAD(cur, R, 4 + cgrp);
      }
#pragma unroll
      for (int nj = 0; nj < 4; ++nj)
#pragma unroll
        for (int kk = 0; kk < 2; ++kk)
#pragma unroll
          for (int mi = 0; mi < 4; ++mi)
            acc[mi][nj] = __builtin_amdgcn_mfma_f32_16x16x32_bf16(
                af[mi][kk], bf[nj][kk], acc[mi][nj], 0, 0, 0);
      __syncthreads();
    }
    // tail ks=4, buffer 0, kk=0 only
    {
      bf16x8 af[4];
#pragma unroll
      for (int mi = 0; mi < 4; ++mi)
        af[mi] = *(const bf16x8*)(&S[(wm * 64 + mi * 16 + r16) * 296 + 256 + kb]);
#pragma unroll
      for (int nj = 0; nj < 4; ++nj) {
        const int R = wn * 64 + nj * 16 + r16;
        bf16x8 bf = BREAD(0, R, cgrp);
#pragma unroll
        for (int mi = 0; mi < 4; ++mi)
          acc[mi][nj] = __builtin_amdgcn_mfma_f32_16x16x32_bf16(
              af[mi], bf, acc[mi][nj], 0, 0, 0);
      }
    }
    float* O = out + (long)ni * 65536 + (long)(half * 128 + wm * 64) * 256 + wn * 64;
#pragma unroll
    for (int mi = 0; mi < 4; ++mi)
#pragma unroll
      for (int nj = 0; nj < 4; ++nj)
#pragma unroll
        for (int q = 0; q < 4; ++q)
          O[(long)(mi * 16 + rr + q) * 256 + nj * 16 + r16] = acc[mi][nj][q];
  }
#undef STG_FULL
#undef STG_TAIL
#undef BREAD
}

extern "C" void kernel_launch(void* const* d_in, const int* in_sizes, int n_in,
                              void* d_out, int out_size, void* d_ws, size_t ws_size,
                              hipStream_t stream) {
  const float* l1 = (const float*)d_in[0];
  const float* l2 = (const float*)d_in[1];
  const float* l3 = (const float*)d_in[2];
  const float* W = (const float*)d_in[3];
  float* out = (float*)d_out;
  char* ws = (char*)d_ws;

  const long LB = 512L * 288 * 2;
  u16* l1b = (u16*)ws;
  u16* l2b = (u16*)(ws + LB);
  u16* l3b = (u16*)(ws + 2 * LB);
  u16* T1 = (u16*)(ws + 3 * LB);  // [512][288c][288b] bf16 = 84.9 MB
  u16* W2 = (u16*)d_out;          // staged in d_out; dead before fused23 writes

  prep_l_kernel<<<1728, 256, 0, stream>>>(l1, l2, l3, l1b, l2b, l3b);

  dim3 gw(9, 9, 288);
  prep_w_kernel<<<gw, 256, 0, stream>>>(W, W2);

  // stage 1: T1[512][(c,b)] = l1b[512][288a] @ W2[(c,b)][288a]^T
  gemm_nt<<<2592, 256, 0, stream>>>(l1b, W2, T1, 288, 288, 288, 82944);

  // fused stage 2+3: two blocks per ni, XCD-paired
  fused23<<<1024, 512, 0, stream>>>(l2b, l3b, T1, out);
}

// Round 7
// 160.421 us; speedup vs baseline: 2.3409x; 1.0222x over previous
//
#include <hip/hip_runtime.h>

typedef unsigned short u16;
typedef __attribute__((ext_vector_type(8))) short bf16x8;
typedef __attribute__((ext_vector_type(4))) float f32x4;

#define GLOAD_LDS16(gsrc, ldst)                                               \
  __builtin_amdgcn_global_load_lds(                                           \
      (const __attribute__((address_space(1))) void*)(gsrc),                  \
      (__attribute__((address_space(3))) void*)(ldst), 16, 0, 0)

#define LDSOFF(p) \
  ((unsigned)(uintptr_t)(__attribute__((address_space(3))) const void*)(p))

__device__ __forceinline__ u16 f2bf(float x) {
  unsigned u = __float_as_uint(x);
  u = (u + 0x7FFFu + ((u >> 16) & 1u)) >> 16;
  return (u16)u;
}

// ---------- prep: l1/l2/l3 -> bf16 [512][288], append 1 at col 256, zero-pad ----------
__global__ void prep_l_kernel(const float* __restrict__ l1,
                              const float* __restrict__ l2,
                              const float* __restrict__ l3,
                              u16* __restrict__ o1, u16* __restrict__ o2,
                              u16* __restrict__ o3) {
  int idx = blockIdx.x * 256 + threadIdx.x;
  const int NR = 512 * 288;
  if (idx >= 3 * NR) return;
  int which = idx / NR, rem = idx - which * NR;
  int r = rem / 288, p = rem - r * 288;
  const float* s = which == 0 ? l1 : which == 1 ? l2 : l3;
  u16* d = which == 0 ? o1 : which == 1 ? o2 : o3;
  float v = (p < 256) ? s[r * 256 + p] : (p == 256 ? 1.0f : 0.0f);
  d[rem] = f2bf(v);
}

// ---------- prep: W[a][b][c] fp32 -> W2[c][b][a] bf16, zero-padded to 288 ----------
__global__ void prep_w_kernel(const float* __restrict__ W, u16* __restrict__ W2) {
  __shared__ float tile[32][33];
  const int a0 = blockIdx.x * 32, c0 = blockIdx.y * 32, b = blockIdx.z;
  const int t = threadIdx.x;
#pragma unroll
  for (int p = 0; p < 4; ++p) {
    int idx = t + p * 256;
    int cl = idx & 31, r = idx >> 5;
    int a = a0 + r, c = c0 + cl;
    float v = 0.0f;
    if (a < 257 && b < 257 && c < 257) v = W[((long)a * 257 + b) * 257 + c];
    tile[r][cl] = v;
  }
  __syncthreads();
#pragma unroll
  for (int p = 0; p < 4; ++p) {
    int idx = t + p * 256;
    int al = idx & 31, ccl = idx >> 5;
    W2[((long)(c0 + ccl) * 288 + b) * 288 + (a0 + al)] = f2bf(tile[al][ccl]);
  }
}

// ---------- stage-1 NT GEMM, BK=64 + both-sides swizzle, XCD-grouped grid ----------
__global__ __launch_bounds__(256) void gemm_nt(
    const u16* __restrict__ A, const u16* __restrict__ B, u16* __restrict__ C,
    int K, int lda, int ldb, int ldc) {
  __shared__ u16 As[128 * 64];
  __shared__ u16 Bs[128 * 64];
  const int t = threadIdx.x;
  const int bid = blockIdx.x;
  const int xcd = bid & 7, s = bid >> 3;
  const int nt = xcd * 81 + (s >> 2);
  const int mt = s & 3;
  const int m0 = mt * 128, n0 = nt * 128;
  const int lane = t & 63;
  const int w = t >> 6;
  const int wr = (w >> 1) * 64, wc = (w & 1) * 64;
  const int r16 = lane & 15;
  const int cgrp = lane >> 4;
  const int rr = cgrp * 4;

  const u16* PA = A + (long)m0 * lda;
  const u16* PB = B + (long)n0 * ldb;

#define STG64(P, ld, dst, k0)                                                 \
  {                                                                           \
    _Pragma("unroll") for (int _p = 0; _p < 4; ++_p) {                        \
      int _q = t + _p * 256;                                                  \
      int _r = _q >> 3, _g = (_q & 7) ^ (_r & 7);                             \
      GLOAD_LDS16(P + (long)_r * (ld) + (k0) + _g * 8, &dst[_q * 8]);         \
    }                                                                         \
  }
#define STG64T(P, ld, dst, k0)                                                \
  {                                                                           \
    _Pragma("unroll") for (int _p = 0; _p < 4; ++_p) {                        \
      int _q = t + _p * 256;                                                  \
      int _r = _q >> 3, _g = (_q & 7) ^ (_r & 7);                             \
      if (_g < 4)                                                             \
        GLOAD_LDS16(P + (long)_r * (ld) + (k0) + _g * 8, &dst[_q * 8]);       \
    }                                                                         \
  }

  f32x4 acc[4][4];
  const f32x4 zero = {0.f, 0.f, 0.f, 0.f};
#pragma unroll
  for (int i = 0; i < 4; ++i)
#pragma unroll
    for (int j = 0; j < 4; ++j) acc[i][j] = zero;

#pragma unroll
  for (int ks = 0; ks < 5; ++ks) {
    const int k0 = ks * 64;
    if (ks < 4) {
      STG64(PA, lda, As, k0);
      STG64(PB, ldb, Bs, k0);
    } else {
      STG64T(PA, lda, As, k0);
      STG64T(PB, ldb, Bs, k0);
    }
    __syncthreads();
    const int nkk = (ks < 4) ? 2 : 1;
#pragma unroll
    for (int kk = 0; kk < 2; ++kk) {
      if (kk < nkk) {
        bf16x8 af[4], bfr[4];
#pragma unroll
        for (int mi = 0; mi < 4; ++mi) {
          int R = wr + mi * 16 + r16;
          af[mi] = *(const bf16x8*)(&As[R * 64 + (((kk * 4 + cgrp) ^ (R & 7)) * 8)]);
        }
#pragma unroll
        for (int ni = 0; ni < 4; ++ni) {
          int R = wc + ni * 16 + r16;
          bfr[ni] = *(const bf16x8*)(&Bs[R * 64 + (((kk * 4 + cgrp) ^ (R & 7)) * 8)]);
        }
#pragma unroll
        for (int mi = 0; mi < 4; ++mi)
#pragma unroll
          for (int ni = 0; ni < 4; ++ni)
            acc[mi][ni] = __builtin_amdgcn_mfma_f32_16x16x32_bf16(
                af[mi], bfr[ni], acc[mi][ni], 0, 0, 0);
      }
    }
    __syncthreads();
  }
#undef STG64
#undef STG64T

#pragma unroll
  for (int mi = 0; mi < 4; ++mi) {
    int gm = m0 + wr + mi * 16 + rr;
#pragma unroll
    for (int ni = 0; ni < 4; ++ni) {
      int gc = n0 + wc + ni * 16 + r16;
#pragma unroll
      for (int r = 0; r < 4; ++r)
        C[(long)(gm + r) * ldc + gc] = f2bf(acc[mi][ni][r]);
    }
  }
}

// ---------- fused stage 2+3: counted-vmcnt 4-slab pipeline (T3+T4) ----------
// Phase A: S[128j][288c] (LDS) = l2[n][jh*128+j][b] . T1[ni][c][b]  (K=b=288)
// Phase B: out[ni][jh*128+j][k] = S[j][c] . l3[n][k][c]             (K=c=288)
// Slab layout: [288 rows][4 chunks of 16B]; chunk (r, g) stored at slot
// g ^ ((r>>2)&3)  -> 64-lane ds_read_b128 is phase-conflict-free (2-way).
__global__ __launch_bounds__(512, 2) void fused23(
    const u16* __restrict__ l2b, const u16* __restrict__ l3b,
    const u16* __restrict__ T1, float* __restrict__ out) {
  __shared__ u16 S[128 * 296];     // 75,776 B
  __shared__ u16 Bst[4][288 * 32]; // 73,728 B (4 slabs x 1152 chunks)
  const int t = threadIdx.x;
  const int lane = t & 63;
  const int w = t >> 6;  // 0..7

  const int bid = blockIdx.x;  // 0..1023, XCD-paired: both halves of ni on one XCD
  const int xcd = bid & 7;
  const int seq = bid >> 3;
  const int ni = xcd * 64 + (seq >> 1);
  const int half = seq & 1;
  const int n = ni >> 8;

  const int r16 = lane & 15;
  const int cgrp = lane >> 4;  // 0..3
  const int kb = cgrp * 8;
  const int rr = cgrp * 4;
  const f32x4 zero = {0.f, 0.f, 0.f, 0.f};

  const u16* A2 = l2b + (long)n * 73728 + (long)(half * 128) * 288;  // [128][288]
  const u16* BT = T1 + (long)ni * 82944;                             // [288][288]
  const u16* B3 = l3b + (long)n * 73728;                             // [256][288]
  const unsigned BOF = LDSOFF(&Bst[0][0]);

  // phase-A slab stage: 1152 chunks, wave w owns [w*144, w*144+144): 3 instr/wave
#define ISSUE_A(buf, kk)                                                      \
  {                                                                           \
    int q1 = w * 144 + lane;                                                  \
    int r1 = q1 >> 2, g1 = (q1 & 3) ^ ((r1 >> 2) & 3);                        \
    GLOAD_LDS16(BT + (long)r1 * 288 + (kk) * 32 + g1 * 8, &Bst[(buf)][q1 * 8]); \
    int q2 = q1 + 64;                                                         \
    int r2 = q2 >> 2, g2 = (q2 & 3) ^ ((r2 >> 2) & 3);                        \
    GLOAD_LDS16(BT + (long)r2 * 288 + (kk) * 32 + g2 * 8, &Bst[(buf)][q2 * 8]); \
    if (lane < 16) {                                                          \
      int q3 = w * 144 + 128 + lane;                                          \
      int r3 = q3 >> 2, g3 = (q3 & 3) ^ ((r3 >> 2) & 3);                      \
      GLOAD_LDS16(BT + (long)r3 * 288 + (kk) * 32 + g3 * 8, &Bst[(buf)][q3 * 8]); \
    }                                                                         \
  }
  // phase-B slab stage: 1024 chunks, wave w owns [w*128, w*128+128): 2 instr/wave
#define ISSUE_B(buf, kk)                                                      \
  {                                                                           \
    int q1 = w * 128 + lane;                                                  \
    int r1 = q1 >> 2, g1 = (q1 & 3) ^ ((r1 >> 2) & 3);                        \
    GLOAD_LDS16(B3 + (long)r1 * 288 + (kk) * 32 + g1 * 8, &Bst[(buf)][q1 * 8]); \
    int q2 = q1 + 64;                                                         \
    int r2 = q2 >> 2, g2 = (q2 & 3) ^ ((r2 >> 2) & 3);                        \
    GLOAD_LDS16(B3 + (long)r2 * 288 + (kk) * 32 + g2 * 8, &Bst[(buf)][q2 * 8]); \
  }

  // ================= phase A =================
  {
    const int wm = w & 3, wn = w >> 2;
    f32x4 acc[2][9];
#pragma unroll
    for (int i = 0; i < 2; ++i)
#pragma unroll
      for (int j = 0; j < 9; ++j) acc[i][j] = zero;

    // preload all l2 A-fragments (18 x bf16x8 = 72 VGPR)
    bf16x8 afr[18];
#pragma unroll
    for (int k = 0; k < 9; ++k)
#pragma unroll
      for (int mi = 0; mi < 2; ++mi)
        afr[k * 2 + mi] = *(const bf16x8*)(A2 +
            (long)(wm * 32 + mi * 16 + r16) * 288 + k * 32 + kb);

    ISSUE_A(0, 0);
    ISSUE_A(1, 1);

    // N waits (instr units; ISSUE_A = 3): k0..k6: 6 (leave S(k+1),S(k+2));
    // k7: 3; k8: 0. k0's wait also drains the 18 afr loads + S0 (suffix rule).
#define FA_STEP(K, NW)                                                        \
  {                                                                           \
    if ((K) + 2 <= 8) ISSUE_A(((K) + 2) & 3, (K) + 2);                        \
    asm volatile("s_waitcnt vmcnt(" #NW ")" ::: "memory");                    \
    __builtin_amdgcn_sched_barrier(0);                                        \
    __builtin_amdgcn_s_barrier();                                             \
    __builtin_amdgcn_sched_barrier(0);                                        \
    bf16x8 bf[9];                                                             \
    _Pragma("unroll") for (int nj = 0; nj < 9; ++nj) {                        \
      const int R = wn * 144 + nj * 16 + r16;                                 \
      unsigned ao = BOF + (unsigned)((((K) & 3) * 9216 + R * 32 +             \
                                      ((cgrp ^ ((R >> 2) & 3)) * 8)) * 2);    \
      asm volatile("ds_read_b128 %0, %1" : "=v"(bf[nj]) : "v"(ao));           \
    }                                                                         \
    asm volatile("s_waitcnt lgkmcnt(0)" ::: "memory");                        \
    __builtin_amdgcn_sched_barrier(0);                                        \
    _Pragma("unroll") for (int nj = 0; nj < 9; ++nj) {                        \
      acc[0][nj] = __builtin_amdgcn_mfma_f32_16x16x32_bf16(                   \
          afr[(K) * 2 + 0], bf[nj], acc[0][nj], 0, 0, 0);                     \
      acc[1][nj] = __builtin_amdgcn_mfma_f32_16x16x32_bf16(                   \
          afr[(K) * 2 + 1], bf[nj], acc[1][nj], 0, 0, 0);                     \
    }                                                                         \
  }
    FA_STEP(0, 6) FA_STEP(1, 6) FA_STEP(2, 6) FA_STEP(3, 6) FA_STEP(4, 6)
    FA_STEP(5, 6) FA_STEP(6, 6) FA_STEP(7, 3) FA_STEP(8, 0)
#undef FA_STEP

    __syncthreads();  // (a) all slab reads done; Bst reusable
    ISSUE_B(0, 0);
    ISSUE_B(1, 1);
#pragma unroll
    for (int mi = 0; mi < 2; ++mi)
#pragma unroll
      for (int nj = 0; nj < 9; ++nj)
#pragma unroll
        for (int q = 0; q < 4; ++q)
          S[(wm * 32 + mi * 16 + rr + q) * 296 + wn * 144 + nj * 16 + r16] =
              f2bf(acc[mi][nj][q]);
  }
  __syncthreads();  // (b) S visible; B0,B1 drained-complete

  // ================= phase B =================
  {
    const int wm = w & 1, wn = w >> 1;
    f32x4 acc[4][4];
#pragma unroll
    for (int i = 0; i < 4; ++i)
#pragma unroll
      for (int j = 0; j < 4; ++j) acc[i][j] = zero;

    // N waits (ISSUE_B = 2): k0..k6: 4; k7: 2; k8: 0.
#define FB_STEP(K, NW)                                                        \
  {                                                                           \
    if ((K) + 2 <= 8) ISSUE_B(((K) + 2) & 3, (K) + 2);                        \
    asm volatile("s_waitcnt vmcnt(" #NW ")" ::: "memory");                    \
    __builtin_amdgcn_sched_barrier(0);                                        \
    __builtin_amdgcn_s_barrier();                                             \
    __builtin_amdgcn_sched_barrier(0);                                        \
    bf16x8 bf[4];                                                             \
    _Pragma("unroll") for (int nj = 0; nj < 4; ++nj) {                        \
      const int R = wn * 64 + nj * 16 + r16;                                  \
      unsigned ao = BOF + (unsigned)((((K) & 3) * 9216 + R * 32 +             \
                                      ((cgrp ^ ((R >> 2) & 3)) * 8)) * 2);    \
      asm volatile("ds_read_b128 %0, %1" : "=v"(bf[nj]) : "v"(ao));           \
    }                                                                         \
    asm volatile("s_waitcnt lgkmcnt(0)" ::: "memory");                        \
    __builtin_amdgcn_sched_barrier(0);                                        \
    bf16x8 af[4];                                                             \
    _Pragma("unroll") for (int mi = 0; mi < 4; ++mi)                          \
      af[mi] = *(const bf16x8*)(&S[(wm * 64 + mi * 16 + r16) * 296 +          \
                                   (K) * 32 + kb]);                           \
    _Pragma("unroll") for (int nj = 0; nj < 4; ++nj)                          \
      _Pragma("unroll") for (int mi = 0; mi < 4; ++mi)                        \
        acc[mi][nj] = __builtin_amdgcn_mfma_f32_16x16x32_bf16(                \
            af[mi], bf[nj], acc[mi][nj], 0, 0, 0);                            \
  }
    FB_STEP(0, 4) FB_STEP(1, 4) FB_STEP(2, 4) FB_STEP(3, 4) FB_STEP(4, 4)
    FB_STEP(5, 4) FB_STEP(6, 4) FB_STEP(7, 2) FB_STEP(8, 0)
#undef FB_STEP

    float* O = out + (long)ni * 65536 + (long)(half * 128 + wm * 64) * 256 + wn * 64;
#pragma unroll
    for (int mi = 0; mi < 4; ++mi)
#pragma unroll
      for (int nj = 0; nj < 4; ++nj)
#pragma unroll
        for (int q = 0; q < 4; ++q)
          O[(long)(mi * 16 + rr + q) * 256 + nj * 16 + r16] = acc[mi][nj][q];
  }
#undef ISSUE_A
#undef ISSUE_B
}

extern "C" void kernel_launch(void* const* d_in, const int* in_sizes, int n_in,
                              void* d_out, int out_size, void* d_ws, size_t ws_size,
                              hipStream_t stream) {
  const float* l1 = (const float*)d_in[0];
  const float* l2 = (const float*)d_in[1];
  const float* l3 = (const float*)d_in[2];
  const float* W = (const float*)d_in[3];
  float* out = (float*)d_out;
  char* ws = (char*)d_ws;

  const long LB = 512L * 288 * 2;
  u16* l1b = (u16*)ws;
  u16* l2b = (u16*)(ws + LB);
  u16* l3b = (u16*)(ws + 2 * LB);
  u16* T1 = (u16*)(ws + 3 * LB);  // [512][288c][288b] bf16 = 84.9 MB
  u16* W2 = (u16*)d_out;          // staged in d_out; dead before fused23 writes

  prep_l_kernel<<<1728, 256, 0, stream>>>(l1, l2, l3, l1b, l2b, l3b);

  dim3 gw(9, 9, 288);
  prep_w_kernel<<<gw, 256, 0, stream>>>(W, W2);

  // stage 1: T1[512][(c,b)] = l1b[512][288a] @ W2[(c,b)][288a]^T
  gemm_nt<<<2592, 256, 0, stream>>>(l1b, W2, T1, 288, 288, 288, 82944);

  // fused stage 2+3: two blocks per ni, XCD-paired
  fused23<<<1024, 512, 0, stream>>>(l2b, l3b, T1, out);
}

// Round 8
// 159.113 us; speedup vs baseline: 2.3602x; 1.0082x over previous
//
#include <hip/hip_runtime.h>

typedef unsigned short u16;
typedef __attribute__((ext_vector_type(8))) short bf16x8;
typedef __attribute__((ext_vector_type(4))) float f32x4;

#define GLOAD_LDS16(gsrc, ldst)                                               \
  __builtin_amdgcn_global_load_lds(                                           \
      (const __attribute__((address_space(1))) void*)(gsrc),                  \
      (__attribute__((address_space(3))) void*)(ldst), 16, 0, 0)

#define LDSOFF(p) \
  ((unsigned)(uintptr_t)(__attribute__((address_space(3))) const void*)(p))

#define SB0 __builtin_amdgcn_sched_barrier(0)

__device__ __forceinline__ u16 f2bf(float x) {
  unsigned u = __float_as_uint(x);
  u = (u + 0x7FFFu + ((u >> 16) & 1u)) >> 16;
  return (u16)u;
}

// ---------- prep: l1/l2/l3 -> bf16 [512][288], append 1 at col 256, zero-pad ----------
__global__ void prep_l_kernel(const float* __restrict__ l1,
                              const float* __restrict__ l2,
                              const float* __restrict__ l3,
                              u16* __restrict__ o1, u16* __restrict__ o2,
                              u16* __restrict__ o3) {
  int idx = blockIdx.x * 256 + threadIdx.x;
  const int NR = 512 * 288;
  if (idx >= 3 * NR) return;
  int which = idx / NR, rem = idx - which * NR;
  int r = rem / 288, p = rem - r * 288;
  const float* s = which == 0 ? l1 : which == 1 ? l2 : l3;
  u16* d = which == 0 ? o1 : which == 1 ? o2 : o3;
  float v = (p < 256) ? s[r * 256 + p] : (p == 256 ? 1.0f : 0.0f);
  d[rem] = f2bf(v);
}

// ---------- prep: W[a][b][c] fp32 -> W2[c][b][a] bf16, zero-padded to 288 ----------
__global__ void prep_w_kernel(const float* __restrict__ W, u16* __restrict__ W2) {
  __shared__ float tile[32][33];
  const int a0 = blockIdx.x * 32, c0 = blockIdx.y * 32, b = blockIdx.z;
  const int t = threadIdx.x;
#pragma unroll
  for (int p = 0; p < 4; ++p) {
    int idx = t + p * 256;
    int cl = idx & 31, r = idx >> 5;
    int a = a0 + r, c = c0 + cl;
    float v = 0.0f;
    if (a < 257 && b < 257 && c < 257) v = W[((long)a * 257 + b) * 257 + c];
    tile[r][cl] = v;
  }
  __syncthreads();
#pragma unroll
  for (int p = 0; p < 4; ++p) {
    int idx = t + p * 256;
    int al = idx & 31, ccl = idx >> 5;
    W2[((long)(c0 + ccl) * 288 + b) * 288 + (a0 + al)] = f2bf(tile[al][ccl]);
  }
}

// ---------- stage-1 NT GEMM: counted-vmcnt dbuf pipeline, BK=32, 1 barrier/step ----------
// C[512][82944] = A[512][288] * B[82944][288]^T; XCD-grouped n-tile-major grid.
// Tile layout: row = 32 u16, 4 chunks of 16B; chunk (r,g) at slot g^((r>>1)&3):
// 64-lane ds_read_b128 hits all 8 bank-groups under fixed lane grouping.
__global__ __launch_bounds__(256, 4) void gemm_nt(
    const u16* __restrict__ A, const u16* __restrict__ B, u16* __restrict__ C,
    int K, int lda, int ldb, int ldc) {
  __shared__ u16 As[2][4096];
  __shared__ u16 Bs[2][4096];
  const int t = threadIdx.x;
  const int bid = blockIdx.x;
  const int xcd = bid & 7, sq = bid >> 3;
  const int nt = xcd * 81 + (sq >> 2);
  const int mt = sq & 3;
  const int m0 = mt * 128, n0 = nt * 128;
  const int lane = t & 63;
  const int w = t >> 6;
  const int wr = (w >> 1) * 64, wc = (w & 1) * 64;
  const int r16 = lane & 15;
  const int cgrp = lane >> 4;
  const int rr = cgrp * 4;
  const unsigned ABase = LDSOFF(&As[0][0]);
  const unsigned BBase = LDSOFF(&Bs[0][0]);
  (void)K;

  const u16* PA = A + (long)m0 * lda;
  const u16* PB = B + (long)n0 * ldb;

#define STG(buf, k0)                                                          \
  {                                                                           \
    _Pragma("unroll") for (int _p = 0; _p < 2; ++_p) {                        \
      int _q = t + _p * 256;                                                  \
      int _r = _q >> 2, _g = (_q & 3) ^ ((_r >> 1) & 3);                      \
      GLOAD_LDS16(PA + (long)_r * lda + (k0) + _g * 8, &As[buf][_q * 8]);     \
      GLOAD_LDS16(PB + (long)_r * ldb + (k0) + _g * 8, &Bs[buf][_q * 8]);     \
    }                                                                         \
  }

  f32x4 acc[4][4];
  const f32x4 zero = {0.f, 0.f, 0.f, 0.f};
#pragma unroll
  for (int i = 0; i < 4; ++i)
#pragma unroll
    for (int j = 0; j < 4; ++j) acc[i][j] = zero;

  STG(0, 0);

#define GCOL(NI)                                                              \
  __builtin_amdgcn_s_setprio(1);                                              \
  acc[0][NI] = __builtin_amdgcn_mfma_f32_16x16x32_bf16(af[0], bf[NI], acc[0][NI], 0, 0, 0); \
  acc[1][NI] = __builtin_amdgcn_mfma_f32_16x16x32_bf16(af[1], bf[NI], acc[1][NI], 0, 0, 0); \
  acc[2][NI] = __builtin_amdgcn_mfma_f32_16x16x32_bf16(af[2], bf[NI], acc[2][NI], 0, 0, 0); \
  acc[3][NI] = __builtin_amdgcn_mfma_f32_16x16x32_bf16(af[3], bf[NI], acc[3][NI], 0, 0, 0); \
  __builtin_amdgcn_s_setprio(0);                                              \
  SB0;

#define GSTEP(KS, NW)                                                         \
  {                                                                           \
    if ((KS) < 8) STG(((KS) + 1) & 1, ((KS) + 1) * 32);                       \
    asm volatile("s_waitcnt vmcnt(" #NW ")" ::: "memory");                    \
    SB0;                                                                      \
    __builtin_amdgcn_s_barrier();                                             \
    SB0;                                                                      \
    bf16x8 af[4], bf[4];                                                      \
    _Pragma("unroll") for (int mi = 0; mi < 4; ++mi) {                        \
      int R = wr + mi * 16 + r16;                                             \
      unsigned ao = ABase + (unsigned)(((((KS) & 1) * 4096) + R * 32 +        \
                                       ((cgrp ^ ((R >> 1) & 3)) * 8)) * 2);   \
      asm volatile("ds_read_b128 %0, %1" : "=v"(af[mi]) : "v"(ao));           \
    }                                                                         \
    _Pragma("unroll") for (int ni = 0; ni < 4; ++ni) {                        \
      int R = wc + ni * 16 + r16;                                             \
      unsigned ao = BBase + (unsigned)(((((KS) & 1) * 4096) + R * 32 +        \
                                       ((cgrp ^ ((R >> 1) & 3)) * 8)) * 2);   \
      asm volatile("ds_read_b128 %0, %1" : "=v"(bf[ni]) : "v"(ao));           \
    }                                                                         \
    SB0;                                                                      \
    asm volatile("s_waitcnt lgkmcnt(3)" ::: "memory"); SB0;                   \
    GCOL(0)                                                                   \
    asm volatile("s_waitcnt lgkmcnt(2)" ::: "memory"); SB0;                   \
    GCOL(1)                                                                   \
    asm volatile("s_waitcnt lgkmcnt(1)" ::: "memory"); SB0;                   \
    GCOL(2)                                                                   \
    asm volatile("s_waitcnt lgkmcnt(0)" ::: "memory"); SB0;                   \
    GCOL(3)                                                                   \
  }

  GSTEP(0, 4) GSTEP(1, 4) GSTEP(2, 4) GSTEP(3, 4) GSTEP(4, 4)
  GSTEP(5, 4) GSTEP(6, 4) GSTEP(7, 4) GSTEP(8, 0)
#undef GSTEP
#undef GCOL
#undef STG

#pragma unroll
  for (int mi = 0; mi < 4; ++mi) {
    int gm = m0 + wr + mi * 16 + rr;
#pragma unroll
    for (int ni = 0; ni < 4; ++ni) {
      int gc = n0 + wc + ni * 16 + r16;
#pragma unroll
      for (int r = 0; r < 4; ++r)
        C[(long)(gm + r) * ldc + gc] = f2bf(acc[mi][ni][r]);
    }
  }
}

// ---------- fused stage 2+3: counted-vmcnt 4-slab pipeline, partial lgkm waits ----------
// Phase A: S[128j][288c] (LDS) = l2[n][jh*128+j][b] . T1[ni][c][b]  (K=b=288)
// Phase B: out[ni][jh*128+j][k] = S[j][c] . l3[n][k][c]             (K=c=288)
// Slab: [288 rows][4 chunks]; chunk (r,g) at slot g^((r>>1)&3) (conflict-free).
__global__ __launch_bounds__(512, 2) void fused23(
    const u16* __restrict__ l2b, const u16* __restrict__ l3b,
    const u16* __restrict__ T1, float* __restrict__ out) {
  __shared__ u16 S[128 * 296];     // 75,776 B
  __shared__ u16 Bst[4][288 * 32]; // 73,728 B
  const int t = threadIdx.x;
  const int lane = t & 63;
  const int w = t >> 6;  // 0..7

  const int bid = blockIdx.x;  // XCD-paired: both halves of ni on one XCD
  const int xcd = bid & 7;
  const int seq = bid >> 3;
  const int ni = xcd * 64 + (seq >> 1);
  const int half = seq & 1;
  const int n = ni >> 8;

  const int r16 = lane & 15;
  const int cgrp = lane >> 4;  // 0..3
  const int kb = cgrp * 8;
  const int rr = cgrp * 4;
  const f32x4 zero = {0.f, 0.f, 0.f, 0.f};

  const u16* A2 = l2b + (long)n * 73728 + (long)(half * 128) * 288;  // [128][288]
  const u16* BT = T1 + (long)ni * 82944;                             // [288][288]
  const u16* B3 = l3b + (long)n * 73728;                             // [256][288]
  const unsigned BOF = LDSOFF(&Bst[0][0]);
  const unsigned SOF = LDSOFF(&S[0]);

#define ISSUE_A(buf, kk)                                                      \
  {                                                                           \
    int q1 = w * 144 + lane;                                                  \
    int r1 = q1 >> 2, g1 = (q1 & 3) ^ ((r1 >> 1) & 3);                        \
    GLOAD_LDS16(BT + (long)r1 * 288 + (kk) * 32 + g1 * 8, &Bst[(buf)][q1 * 8]); \
    int q2 = q1 + 64;                                                         \
    int r2 = q2 >> 2, g2 = (q2 & 3) ^ ((r2 >> 1) & 3);                        \
    GLOAD_LDS16(BT + (long)r2 * 288 + (kk) * 32 + g2 * 8, &Bst[(buf)][q2 * 8]); \
    if (lane < 16) {                                                          \
      int q3 = w * 144 + 128 + lane;                                          \
      int r3 = q3 >> 2, g3 = (q3 & 3) ^ ((r3 >> 1) & 3);                      \
      GLOAD_LDS16(BT + (long)r3 * 288 + (kk) * 32 + g3 * 8, &Bst[(buf)][q3 * 8]); \
    }                                                                         \
  }
#define ISSUE_B(buf, kk)                                                      \
  {                                                                           \
    int q1 = w * 128 + lane;                                                  \
    int r1 = q1 >> 2, g1 = (q1 & 3) ^ ((r1 >> 1) & 3);                        \
    GLOAD_LDS16(B3 + (long)r1 * 288 + (kk) * 32 + g1 * 8, &Bst[(buf)][q1 * 8]); \
    int q2 = q1 + 64;                                                         \
    int r2 = q2 >> 2, g2 = (q2 & 3) ^ ((r2 >> 1) & 3);                        \
    GLOAD_LDS16(B3 + (long)r2 * 288 + (kk) * 32 + g2 * 8, &Bst[(buf)][q2 * 8]); \
  }

  // ================= phase A =================
  {
    const int wm = w & 3, wn = w >> 2;
    f32x4 acc[2][9];
#pragma unroll
    for (int i = 0; i < 2; ++i)
#pragma unroll
      for (int j = 0; j < 9; ++j) acc[i][j] = zero;

    // preload all l2 A-fragments (18 x bf16x8 = 72 VGPR)
    bf16x8 afr[18];
#pragma unroll
    for (int k = 0; k < 9; ++k)
#pragma unroll
      for (int mi = 0; mi < 2; ++mi)
        afr[k * 2 + mi] = *(const bf16x8*)(A2 +
            (long)(wm * 32 + mi * 16 + r16) * 288 + k * 32 + kb);
    SB0;

    ISSUE_A(0, 0);
    ISSUE_A(1, 1);

#define FA_MM(NJ)                                                             \
  __builtin_amdgcn_s_setprio(1);                                              \
  acc[0][NJ] = __builtin_amdgcn_mfma_f32_16x16x32_bf16(afc0, bf[NJ], acc[0][NJ], 0, 0, 0); \
  acc[1][NJ] = __builtin_amdgcn_mfma_f32_16x16x32_bf16(afc1, bf[NJ], acc[1][NJ], 0, 0, 0); \
  __builtin_amdgcn_s_setprio(0);

#define FA_STEP(K, NW)                                                        \
  {                                                                           \
    if ((K) + 2 <= 8) ISSUE_A(((K) + 2) & 3, (K) + 2);                        \
    asm volatile("s_waitcnt vmcnt(" #NW ")" ::: "memory");                    \
    SB0;                                                                      \
    __builtin_amdgcn_s_barrier();                                             \
    SB0;                                                                      \
    bf16x8 bf[9];                                                             \
    _Pragma("unroll") for (int nj = 0; nj < 9; ++nj) {                        \
      const int R = wn * 144 + nj * 16 + r16;                                 \
      unsigned ao = BOF + (unsigned)((((K) & 3) * 9216 + R * 32 +             \
                                      ((cgrp ^ ((R >> 1) & 3)) * 8)) * 2);    \
      asm volatile("ds_read_b128 %0, %1" : "=v"(bf[nj]) : "v"(ao));           \
    }                                                                         \
    SB0;                                                                      \
    const bf16x8 afc0 = afr[(K) * 2 + 0], afc1 = afr[(K) * 2 + 1];            \
    asm volatile("s_waitcnt lgkmcnt(6)" ::: "memory"); SB0;                   \
    FA_MM(0) FA_MM(1) FA_MM(2) SB0;                                           \
    asm volatile("s_waitcnt lgkmcnt(3)" ::: "memory"); SB0;                   \
    FA_MM(3) FA_MM(4) FA_MM(5) SB0;                                           \
    asm volatile("s_waitcnt lgkmcnt(0)" ::: "memory"); SB0;                   \
    FA_MM(6) FA_MM(7) FA_MM(8) SB0;                                           \
  }
    FA_STEP(0, 6) FA_STEP(1, 6) FA_STEP(2, 6) FA_STEP(3, 6) FA_STEP(4, 6)
    FA_STEP(5, 6) FA_STEP(6, 6) FA_STEP(7, 3) FA_STEP(8, 0)
#undef FA_STEP
#undef FA_MM

    __syncthreads();  // all slab reads done; Bst reusable
    ISSUE_B(0, 0);
    ISSUE_B(1, 1);
#pragma unroll
    for (int mi = 0; mi < 2; ++mi)
#pragma unroll
      for (int nj = 0; nj < 9; ++nj)
#pragma unroll
        for (int q = 0; q < 4; ++q)
          S[(wm * 32 + mi * 16 + rr + q) * 296 + wn * 144 + nj * 16 + r16] =
              f2bf(acc[mi][nj][q]);
  }
  __syncthreads();  // S visible

  // ================= phase B =================
  {
    const int wm = w & 1, wn = w >> 1;
    f32x4 acc[4][4];
#pragma unroll
    for (int i = 0; i < 4; ++i)
#pragma unroll
      for (int j = 0; j < 4; ++j) acc[i][j] = zero;

#define FB_MM(NI)                                                             \
  __builtin_amdgcn_s_setprio(1);                                              \
  acc[0][NI] = __builtin_amdgcn_mfma_f32_16x16x32_bf16(af[0], bf[NI], acc[0][NI], 0, 0, 0); \
  acc[1][NI] = __builtin_amdgcn_mfma_f32_16x16x32_bf16(af[1], bf[NI], acc[1][NI], 0, 0, 0); \
  acc[2][NI] = __builtin_amdgcn_mfma_f32_16x16x32_bf16(af[2], bf[NI], acc[2][NI], 0, 0, 0); \
  acc[3][NI] = __builtin_amdgcn_mfma_f32_16x16x32_bf16(af[3], bf[NI], acc[3][NI], 0, 0, 0); \
  __builtin_amdgcn_s_setprio(0);                                              \
  SB0;

#define FB_STEP(K, NW)                                                        \
  {                                                                           \
    if ((K) + 2 <= 8) ISSUE_B(((K) + 2) & 3, (K) + 2);                        \
    asm volatile("s_waitcnt vmcnt(" #NW ")" ::: "memory");                    \
    SB0;                                                                      \
    __builtin_amdgcn_s_barrier();                                             \
    SB0;                                                                      \
    bf16x8 af[4], bf[4];                                                      \
    _Pragma("unroll") for (int mi = 0; mi < 4; ++mi) {                        \
      unsigned ao = SOF + (unsigned)(((wm * 64 + mi * 16 + r16) * 296 +       \
                                      (K) * 32 + kb) * 2);                    \
      asm volatile("ds_read_b128 %0, %1" : "=v"(af[mi]) : "v"(ao));           \
    }                                                                         \
    _Pragma("unroll") for (int nj = 0; nj < 4; ++nj) {                        \
      const int R = wn * 64 + nj * 16 + r16;                                  \
      unsigned ao = BOF + (unsigned)((((K) & 3) * 9216 + R * 32 +             \
                                      ((cgrp ^ ((R >> 1) & 3)) * 8)) * 2);    \
      asm volatile("ds_read_b128 %0, %1" : "=v"(bf[nj]) : "v"(ao));           \
    }                                                                         \
    SB0;                                                                      \
    asm volatile("s_waitcnt lgkmcnt(3)" ::: "memory"); SB0;                   \
    FB_MM(0)                                                                  \
    asm volatile("s_waitcnt lgkmcnt(2)" ::: "memory"); SB0;                   \
    FB_MM(1)                                                                  \
    asm volatile("s_waitcnt lgkmcnt(1)" ::: "memory"); SB0;                   \
    FB_MM(2)                                                                  \
    asm volatile("s_waitcnt lgkmcnt(0)" ::: "memory"); SB0;                   \
    FB_MM(3)                                                                  \
  }
    FB_STEP(0, 4) FB_STEP(1, 4) FB_STEP(2, 4) FB_STEP(3, 4) FB_STEP(4, 4)
    FB_STEP(5, 4) FB_STEP(6, 4) FB_STEP(7, 2) FB_STEP(8, 0)
#undef FB_STEP
#undef FB_MM

    float* O = out + (long)ni * 65536 + (long)(half * 128 + wm * 64) * 256 + wn * 64;
#pragma unroll
    for (int mi = 0; mi < 4; ++mi)
#pragma unroll
      for (int nj = 0; nj < 4; ++nj)
#pragma unroll
        for (int q = 0; q < 4; ++q)
          O[(long)(mi * 16 + rr + q) * 256 + nj * 16 + r16] = acc[mi][nj][q];
  }
#undef ISSUE_A
#undef ISSUE_B
}

extern "C" void kernel_launch(void* const* d_in, const int* in_sizes, int n_in,
                              void* d_out, int out_size, void* d_ws, size_t ws_size,
                              hipStream_t stream) {
  const float* l1 = (const float*)d_in[0];
  const float* l2 = (const float*)d_in[1];
  const float* l3 = (const float*)d_in[2];
  const float* W = (const float*)d_in[3];
  float* out = (float*)d_out;
  char* ws = (char*)d_ws;

  const long LB = 512L * 288 * 2;
  u16* l1b = (u16*)ws;
  u16* l2b = (u16*)(ws + LB);
  u16* l3b = (u16*)(ws + 2 * LB);
  u16* T1 = (u16*)(ws + 3 * LB);  // [512][288c][288b] bf16 = 84.9 MB
  u16* W2 = (u16*)d_out;          // staged in d_out; dead before fused23 writes

  prep_l_kernel<<<1728, 256, 0, stream>>>(l1, l2, l3, l1b, l2b, l3b);

  dim3 gw(9, 9, 288);
  prep_w_kernel<<<gw, 256, 0, stream>>>(W, W2);

  // stage 1: T1[512][(c,b)] = l1b[512][288a] @ W2[(c,b)][288a]^T
  gemm_nt<<<2592, 256, 0, stream>>>(l1b, W2, T1, 288, 288, 288, 82944);

  // fused stage 2+3: two blocks per ni, XCD-paired
  fused23<<<1024, 512, 0, stream>>>(l2b, l3b, T1, out);
}